// Round 6
// baseline (538.102 us; speedup 1.0000x reference)
//
#include <hip/hip_runtime.h>
#include <hip/hip_bf16.h>

typedef __hip_bfloat16 bf16;
typedef __attribute__((ext_vector_type(8))) short bf16x8;   // 8 bf16 (4 VGPRs)
typedef __attribute__((ext_vector_type(4))) float f32x4;    // MFMA accum

__device__ __forceinline__ float b2f(bf16 v) { return __bfloat162float(v); }
__device__ __forceinline__ bf16 f2b(float v) { return __float2bfloat16(v); }

// Scalar load/store from an external buffer whose dtype is decided by isb.
__device__ __forceinline__ float ldx(const void* p, size_t i, bool isb) {
    return isb ? b2f(((const bf16*)p)[i]) : ((const float*)p)[i];
}
__device__ __forceinline__ void stx(void* p, size_t i, bool isb, float v) {
    if (isb) ((bf16*)p)[i] = f2b(v);
    else     ((float*)p)[i] = v;
}
// Vector (8-elem) external load; i must be a multiple of 8.
__device__ __forceinline__ void ldx8(const void* p, size_t i, bool isb, float* o) {
    if (isb) {
        const bf16x8 v = *(const bf16x8*)((const bf16*)p + i);
#pragma unroll
        for (int j = 0; j < 8; j++) o[j] = b2f(((const bf16*)&v)[j]);
    } else {
        const float4 v0 = *(const float4*)((const float*)p + i);
        const float4 v1 = *(const float4*)((const float*)p + i + 4);
        o[0]=v0.x; o[1]=v0.y; o[2]=v0.z; o[3]=v0.w;
        o[4]=v1.x; o[5]=v1.y; o[6]=v1.z; o[7]=v1.w;
    }
}

// ---------------------------------------------------------------------------
// Dtype sniffer (verified round 3): decides fp32 vs bf16 external data.
// ---------------------------------------------------------------------------
__global__ void sniff_kernel(const void* __restrict__ x, int* __restrict__ flag) {
    const unsigned* w = (const unsigned*)x;
    const int t = threadIdx.x;
    int cnt = 0;
#pragma unroll
    for (int i = 0; i < 4; i++) {
        const unsigned word = w[t * 4 + i];
        const int e = (word >> 23) & 0xFF;
        cnt += (e >= 192) ? 1 : 0;
    }
    __shared__ int red[4];
#pragma unroll
    for (int o = 32; o > 0; o >>= 1) cnt += __shfl_down(cnt, o);
    if ((t & 63) == 0) red[t >> 6] = cnt;
    __syncthreads();
    if (t == 0) flag[0] = ((red[0] + red[1] + red[2] + red[3]) >= 512) ? 1 : 0;
}

// ---------------------------------------------------------------------------
// Merged weight convert+transpose for BOTH attention phases in one dispatch:
// grid (16,16,8): z 0..3 = SA {wq, wkv-lo, wkv-hi, wo} -> WT*, z 4..7 = CA
// -> WT2*. 64x64 LDS-tiled transpose, K=1024 for all.
// ---------------------------------------------------------------------------
__global__ void wconv8_kernel(const void* __restrict__ Wq,
                              const void* __restrict__ Wkv,
                              const void* __restrict__ Wo,
                              const void* __restrict__ Wq2,
                              const void* __restrict__ Wkv2,
                              const void* __restrict__ Wo2,
                              bf16* __restrict__ WTq, bf16* __restrict__ WTkv,
                              bf16* __restrict__ WTo,
                              bf16* __restrict__ WTq2, bf16* __restrict__ WTkv2,
                              bf16* __restrict__ WTo2,
                              const int* __restrict__ flagp) {
    const bool isb = (*flagp != 0);
    const int z = blockIdx.z;
    const int zz = z & 3;
    const bool ca = z >= 4;
    const void* W = ca ? ((zz == 0) ? Wq2 : (zz == 3) ? Wo2 : Wkv2)
                       : ((zz == 0) ? Wq  : (zz == 3) ? Wo  : Wkv);
    bf16* Wt      = ca ? ((zz == 0) ? WTq2 : (zz == 3) ? WTo2 : WTkv2)
                       : ((zz == 0) ? WTq  : (zz == 3) ? WTo  : WTkv);
    const int N   = (zz == 1 || zz == 2) ? 2048 : 1024;
    const int K = 1024;
    __shared__ float T[64][65];
    const int n0 = blockIdx.x * 64 + ((zz == 2) ? 1024 : 0);
    const int k0 = blockIdx.y * 64;
    const int t = threadIdx.x;
    const int rr = t >> 3, c8 = (t & 7) * 8;
#pragma unroll
    for (int i = 0; i < 2; i++) {
        const int row = rr + i * 32;
        float v[8];
        ldx8(W, (size_t)(k0 + row) * N + n0 + c8, isb, v);
#pragma unroll
        for (int j = 0; j < 8; j++) T[row][c8 + j] = v[j];
    }
    __syncthreads();
#pragma unroll
    for (int i = 0; i < 2; i++) {
        const int row = rr + i * 32;   // n-index within tile
        bf16x8 ov;
#pragma unroll
        for (int j = 0; j < 8; j++) ((bf16*)&ov)[j] = f2b(T[c8 + j][row]);
        *(bf16x8*)(Wt + (size_t)(n0 + row) * K + k0 + c8) = ov;
    }
}

// ---------------------------------------------------------------------------
// LayerNorm over F=1024, batch-fused via grid.z (per-batch strides in elems).
// ---------------------------------------------------------------------------
__global__ void ln_dual_kernel(const void* __restrict__ in, size_t in_off, long in_bs,
                               int in_ext,
                               const void* __restrict__ g1, const void* __restrict__ b1,
                               const void* __restrict__ g2, const void* __restrict__ b2,
                               bf16* __restrict__ out1, bf16* __restrict__ out2,
                               long out_bs, const int* __restrict__ flagp) {
    const int F = 1024;
    const bool isb = (*flagp != 0);
    const bool inb = in_ext ? isb : true;
    const int row = blockIdx.x;
    const int z = blockIdx.z;
    const int t = threadIdx.x;
    const size_t base = in_off + (size_t)z * in_bs + (size_t)row * F;
    const size_t obase = (size_t)z * out_bs + (size_t)row * F;

    float v[4];
    float s = 0.f;
#pragma unroll
    for (int i = 0; i < 4; i++) { v[i] = ldx(in, base + t + 256 * i, inb); s += v[i]; }

    __shared__ float red1[4];
    __shared__ float red2[4];
#pragma unroll
    for (int o = 32; o > 0; o >>= 1) s += __shfl_down(s, o);
    if ((t & 63) == 0) red1[t >> 6] = s;
    __syncthreads();
    const float mean = (red1[0] + red1[1] + red1[2] + red1[3]) * (1.0f / F);

    float ss = 0.f;
#pragma unroll
    for (int i = 0; i < 4; i++) { float d = v[i] - mean; ss += d * d; }
#pragma unroll
    for (int o = 32; o > 0; o >>= 1) ss += __shfl_down(ss, o);
    if ((t & 63) == 0) red2[t >> 6] = ss;
    __syncthreads();
    const float var = (red2[0] + red2[1] + red2[2] + red2[3]) * (1.0f / F);
    const float rn = rsqrtf(var + 1e-5f);

#pragma unroll
    for (int i = 0; i < 4; i++) {
        const int idx = t + 256 * i;
        const float nv = (v[i] - mean) * rn;
        out1[obase + idx] = f2b(nv * ldx(g1, idx, isb) + ldx(b1, idx, isb));
        if (out2) out2[obase + idx] = f2b(nv * ldx(g2, idx, isb) + ldx(b2, idx, isb));
    }
}

// ---------------------------------------------------------------------------
// Grouped fast MFMA GEMM (round-0 verified body, reg-staged, padded LDS).
// C = A[R,1024] @ Bt^T, 128x128 tile, BK=64, 4 waves x 4x4 16x16x32 MFMA.
// Three slots per dispatch (blockIdx.x partitioned) — grouping measured
// positive in rounds 4 and 5. Early return on by>=nby is block-uniform.
// ---------------------------------------------------------------------------
struct GArgs {
    const bf16* A; const bf16* Bt; void* C;
    const void* bias; const void* res;
    bf16* kb0; bf16* kb1;
    int c_ext, res_ext, N, mode, zsplit, zrows, nbx, nby;
};

__global__ __launch_bounds__(256) void gemm_fused(GArgs ga, GArgs gb, GArgs gc,
                                                  const int* __restrict__ flagp) {
    int bx = (int)blockIdx.x;
    GArgs g;
    if (bx < ga.nbx) { g = ga; }
    else if (bx < ga.nbx + gb.nbx) { g = gb; bx -= ga.nbx; }
    else { g = gc; bx -= ga.nbx + gb.nbx; }
    const int by = (int)blockIdx.y;
    if (by >= g.nby) return;               // block-uniform: no divergent barrier

    const int K = 1024;
    const bool isb = (*flagp != 0);

    __shared__ bf16 As[128][72];
    __shared__ bf16 Bs[128][72];

    const int t = threadIdx.x;
    const int w = t >> 6, lane = t & 63, li = lane & 15, quad = lane >> 4;
    const int wm = (w & 1) * 64, wn = (w >> 1) * 64;
    const int bm = by * 128, bn = bx * 128;

    f32x4 acc[4][4];
#pragma unroll
    for (int mi = 0; mi < 4; mi++)
#pragma unroll
        for (int ni = 0; ni < 4; ni++)
#pragma unroll
            for (int r = 0; r < 4; r++) acc[mi][ni][r] = 0.f;

    for (int k0 = 0; k0 < K; k0 += 64) {
#pragma unroll
        for (int c = 0; c < 4; c++) {
            const int d = c * 256 + t;
            const int row = d >> 3, ch = (d & 7) * 8;
            *(bf16x8*)&As[row][ch] = *(const bf16x8*)(g.A + (size_t)(bm + row) * K + k0 + ch);
            *(bf16x8*)&Bs[row][ch] = *(const bf16x8*)(g.Bt + (size_t)(bn + row) * K + k0 + ch);
        }
        __syncthreads();
#pragma unroll
        for (int kc = 0; kc < 2; kc++) {
            bf16x8 af[4], bfr[4];
#pragma unroll
            for (int i = 0; i < 4; i++) {
                af[i]  = *(const bf16x8*)&As[wm + i * 16 + li][kc * 32 + quad * 8];
                bfr[i] = *(const bf16x8*)&Bs[wn + i * 16 + li][kc * 32 + quad * 8];
            }
#pragma unroll
            for (int mi = 0; mi < 4; mi++)
#pragma unroll
                for (int ni = 0; ni < 4; ni++)
                    acc[mi][ni] = __builtin_amdgcn_mfma_f32_16x16x32_bf16(
                        af[mi], bfr[ni], acc[mi][ni], 0, 0, 0);
        }
        __syncthreads();
    }

    if (g.mode == 1) {
#pragma unroll
        for (int mi = 0; mi < 4; mi++)
#pragma unroll
            for (int r = 0; r < 4; r++) {
                const int row = bm + wm + mi * 16 + quad * 4 + r;
                bf16* kb = (row < g.zsplit) ? g.kb0 : g.kb1;
                const int lrow = (row < g.zsplit) ? row : row - g.zsplit;
#pragma unroll
                for (int ni = 0; ni < 4; ni++) {
                    const int col = bn + wn + ni * 16 + li;
                    const float v = acc[mi][ni][r];
                    if (col < 1024)
                        kb[(size_t)lrow * 1024 + col] = f2b(v);
                    else
                        kb[(size_t)1024 * g.zrows + (size_t)(col - 1024) * g.zrows + lrow] = f2b(v);
                }
            }
        return;
    }

#pragma unroll
    for (int mi = 0; mi < 4; mi++)
#pragma unroll
        for (int r = 0; r < 4; r++) {
            const int row = bm + wm + mi * 16 + quad * 4 + r;
#pragma unroll
            for (int ni = 0; ni < 4; ni++) {
                const int col = bn + wn + ni * 16 + li;
                float v = acc[mi][ni][r];
                if (g.bias) v += ldx(g.bias, col, isb);
                if (g.res)  v += ldx(g.res, (size_t)row * g.N + col, g.res_ext ? isb : true);
                stx(g.C, (size_t)row * g.N + col, g.c_ext ? isb : true, v);
            }
        }
}

// ---------------------------------------------------------------------------
// Slow-path MFMA GEMM (round-7 verified, used only if workspace is small).
// ---------------------------------------------------------------------------
__global__ __launch_bounds__(256) void gemm_mfma(
    const bf16* __restrict__ A, long a_bs, const void* __restrict__ W,
    void* __restrict__ C, size_t c_off, long c_bs, int c_ext,
    const void* __restrict__ bias,
    const void* __restrict__ res, size_t res_off, long res_bs, int res_ext,
    int K, int N, int mode, int R,
    bf16* __restrict__ kb0, bf16* __restrict__ kb1,
    const int* __restrict__ flagp) {

    const bool isb = (*flagp != 0);
    const bool resb = res_ext ? isb : true;
    const bool cb = c_ext ? isb : true;
    const int z = blockIdx.z;

    const bf16* Az = A + (size_t)z * a_bs;
    const size_t coz = c_off + (size_t)z * c_bs;
    const size_t roz = res_off + (size_t)z * res_bs;

    __shared__ bf16 As[64][72];
    __shared__ bf16 Bs[64][72];

    const int t = threadIdx.x;
    const int w = t >> 6, lane = t & 63, li = lane & 15, quad = lane >> 4;
    const int wm = (w & 1) * 32, wn = (w >> 1) * 32;
    const int bm = blockIdx.y * 64, bn = blockIdx.x * 64;

    f32x4 acc[2][2];
#pragma unroll
    for (int mi = 0; mi < 2; mi++)
#pragma unroll
        for (int ni = 0; ni < 2; ni++)
#pragma unroll
            for (int r = 0; r < 4; r++) acc[mi][ni][r] = 0.f;

    for (int k0 = 0; k0 < K; k0 += 64) {
#pragma unroll
        for (int c = 0; c < 2; c++) {
            const int lin = t * 16 + c * 8;
            const int row = lin >> 6, kk = lin & 63;
            *(bf16x8*)&As[row][kk] = *(const bf16x8*)(Az + (size_t)(bm + row) * K + k0 + kk);
        }
#pragma unroll
        for (int c = 0; c < 2; c++) {
            const int lin = t * 16 + c * 8;
            const int kk = lin >> 6, n0 = lin & 63;
            float v[8];
            ldx8(W, (size_t)(k0 + kk) * N + bn + n0, isb, v);
            const int st = t & 7;
#pragma unroll
            for (int i = 0; i < 8; i++) {
                const int ii = (i + st) & 7;
                Bs[n0 + ii][kk] = f2b(v[ii]);
            }
        }
        __syncthreads();
#pragma unroll
        for (int kc = 0; kc < 2; kc++) {
            bf16x8 af[2], bfr[2];
#pragma unroll
            for (int mi = 0; mi < 2; mi++)
                af[mi] = *(const bf16x8*)&As[wm + mi * 16 + li][kc * 32 + quad * 8];
#pragma unroll
            for (int ni = 0; ni < 2; ni++)
                bfr[ni] = *(const bf16x8*)&Bs[wn + ni * 16 + li][kc * 32 + quad * 8];
#pragma unroll
            for (int mi = 0; mi < 2; mi++)
#pragma unroll
                for (int ni = 0; ni < 2; ni++)
                    acc[mi][ni] = __builtin_amdgcn_mfma_f32_16x16x32_bf16(
                        af[mi], bfr[ni], acc[mi][ni], 0, 0, 0);
        }
        __syncthreads();
    }

    if (mode == 1) {
        bf16* kb = z ? kb1 : kb0;
#pragma unroll
        for (int mi = 0; mi < 2; mi++)
#pragma unroll
            for (int r = 0; r < 4; r++) {
                const int row = bm + wm + mi * 16 + quad * 4 + r;
#pragma unroll
                for (int ni = 0; ni < 2; ni++) {
                    const int col = bn + wn + ni * 16 + li;
                    const float v = acc[mi][ni][r];
                    if (col < 1024)
                        kb[(size_t)row * 1024 + col] = f2b(v);
                    else
                        kb[(size_t)1024 * R + (size_t)(col - 1024) * R + row] = f2b(v);
                }
            }
        return;
    }

#pragma unroll
    for (int mi = 0; mi < 2; mi++)
#pragma unroll
        for (int r = 0; r < 4; r++) {
            const int row = bm + wm + mi * 16 + quad * 4 + r;
#pragma unroll
            for (int ni = 0; ni < 2; ni++) {
                const int col = bn + wn + ni * 16 + li;
                float v = acc[mi][ni][r];
                if (bias) v += ldx(bias, col, isb);
                if (res)  v += ldx(res, roz + (size_t)row * N + col, resb);
                stx(C, coz + (size_t)row * N + col, cb, v);
            }
        }
}

// ---------------------------------------------------------------------------
// attn_flash: round-0 verified body (best measured: 134.6 µs SA). Used only
// by the fallback path. Shared Ps + setprio, no prefetch.
// ---------------------------------------------------------------------------
__global__ __launch_bounds__(64) void attn_flash(
    const bf16* __restrict__ qb, const bf16* __restrict__ kv0,
    const bf16* __restrict__ kv1,
    const void* __restrict__ rel_emb, bf16* __restrict__ out,
    long qo_bs, long out_bs, int m, int rel_off, const int* __restrict__ flagp) {

    const float SC = 0.125f * 1.44269504f;
    const bool isb = (*flagp != 0);
    const int id = blockIdx.x;
    const int xcd = id & 7;
    const int slot = id >> 3;
    const int c = (slot >> 6) * 8 + xcd;
    const int h = c & 15, z = c >> 4;
    const int q0 = (slot & 63) * 32;
    const int t = threadIdx.x;
    const int li = t & 15, quad = t >> 4;

    const bf16* qz = qb + (size_t)z * qo_bs;
    bf16* oz = out + (size_t)z * out_bs;
    const bf16* kb = z ? kv1 : kv0;
    const bf16* vtb = kb + (size_t)m * 1024;

    __shared__ float bias_s[32];
    __shared__ float tab[2080];
    __shared__ bf16 Ps[16][40];

    if (t < 32) bias_s[t] = ldx(rel_emb, t * 16 + h, isb) * SC - 40.0f;
    __syncthreads();

    const int tsz = m + 31;
    for (int i = t; i < tsz; i += 64) {
        const int rel = i - 31 - q0 + rel_off;
        const int ab = rel < 0 ? -rel : rel;
        int bucket = rel >= 0 ? 16 : 0;
        if (ab < 8) {
            bucket += ab;
        } else {
            const int p = 31 - __clz(ab);
            const int k2 = 2 * p + ((ab * ab >= (1 << (2 * p + 1))) ? 1 : 0);
            const int val = k2 + 2;
            bucket += (val > 15) ? 15 : val;
        }
        tab[i] = bias_s[bucket];
    }
    __syncthreads();

    bf16x8 aq[2][2];
#pragma unroll
    for (int g = 0; g < 2; g++)
#pragma unroll
        for (int kc = 0; kc < 2; kc++)
            aq[g][kc] = *(const bf16x8*)(qz + (size_t)(q0 + g * 16 + li) * 1024
                                         + h * 64 + kc * 32 + quad * 8);

    bf16x8 ones;
#pragma unroll
    for (int j = 0; j < 8; j++) ((short*)&ones)[j] = 0x3F80;

    f32x4 o[2][4], lac[2];
#pragma unroll
    for (int g = 0; g < 2; g++) {
#pragma unroll
        for (int r = 0; r < 4; r++) lac[g][r] = 0.f;
#pragma unroll
        for (int nb = 0; nb < 4; nb++)
#pragma unroll
            for (int r = 0; r < 4; r++) o[g][nb][r] = 0.f;
    }

    for (int j0 = 0; j0 < m; j0 += 32) {
        bf16x8 kf[4], vf[4];
#pragma unroll
        for (int nb = 0; nb < 2; nb++)
#pragma unroll
            for (int kc = 0; kc < 2; kc++)
                kf[nb * 2 + kc] = *(const bf16x8*)(
                    kb + (size_t)(j0 + nb * 16 + li) * 1024 + h * 64 + kc * 32 + quad * 8);
#pragma unroll
        for (int nb = 0; nb < 4; nb++)
            vf[nb] = *(const bf16x8*)(
                vtb + (size_t)(h * 64 + nb * 16 + li) * m + j0 + quad * 8);

#pragma unroll
        for (int g = 0; g < 2; g++) {
            f32x4 s[2];
            __builtin_amdgcn_s_setprio(1);
#pragma unroll
            for (int nb = 0; nb < 2; nb++) {
                f32x4 a;
#pragma unroll
                for (int r = 0; r < 4; r++) a[r] = 0.f;
#pragma unroll
                for (int kc = 0; kc < 2; kc++)
                    a = __builtin_amdgcn_mfma_f32_16x16x32_bf16(aq[g][kc], kf[nb * 2 + kc],
                                                                a, 0, 0, 0);
                s[nb] = a;
            }
            __builtin_amdgcn_s_setprio(0);
#pragma unroll
            for (int nb = 0; nb < 2; nb++)
#pragma unroll
                for (int r = 0; r < 4; r++) {
                    const int ti = j0 + nb * 16 + li + 31 - (g * 16 + quad * 4 + r);
                    s[nb][r] = exp2f(fmaf(s[nb][r], SC, tab[ti]));
                }
#pragma unroll
            for (int nb = 0; nb < 2; nb++)
#pragma unroll
                for (int r = 0; r < 4; r++)
                    Ps[quad * 4 + r][nb * 16 + li] = f2b(s[nb][r]);
            const bf16x8 ap = *(const bf16x8*)&Ps[li][quad * 8];
            __builtin_amdgcn_s_setprio(1);
#pragma unroll
            for (int nb = 0; nb < 4; nb++)
                o[g][nb] = __builtin_amdgcn_mfma_f32_16x16x32_bf16(ap, vf[nb],
                                                                   o[g][nb], 0, 0, 0);
            lac[g] = __builtin_amdgcn_mfma_f32_16x16x32_bf16(ap, ones, lac[g], 0, 0, 0);
            __builtin_amdgcn_s_setprio(0);
        }
    }

#pragma unroll
    for (int g = 0; g < 2; g++)
#pragma unroll
        for (int r = 0; r < 4; r++) {
            const float inv = 1.0f / lac[g][r];
            const int qi = q0 + g * 16 + quad * 4 + r;
#pragma unroll
            for (int nb = 0; nb < 4; nb++)
                oz[(size_t)qi * 1024 + h * 64 + nb * 16 + li] = f2b(o[g][nb][r] * inv);
        }
}

// ---------------------------------------------------------------------------
// ROUND 6: key-split flash attention across INDEPENDENT blocks. Rationale:
// OccupancyPercent pinned at ~22% every round because the grid (2048 blocks
// = 8 waves/CU) IS the cap; three intra-wave scheduling edits all failed.
// Fixed-max softmax => O and l are purely ADDITIVE over keys, so each block
// handles half the keys (no barrier coupling — unlike round 1's shared-block
// split) and writes f32 partials; attn_comb does (O0+O1)/(l0+l1).
// Grid 4096 = 16 waves/CU. Inner body = round-0 verified (best measured).
// LDS: tab sized for m/2+31 <= 1055 -> ~6 KB, not an occupancy limiter.
// ---------------------------------------------------------------------------
__global__ __launch_bounds__(64) void attn_split(
    const bf16* __restrict__ qb, const bf16* __restrict__ kv0,
    const bf16* __restrict__ kv1,
    const void* __restrict__ rel_emb,
    float* __restrict__ po, float* __restrict__ pl,
    long qo_bs, int m, int rel_off, const int* __restrict__ flagp) {

    const float SC = 0.125f * 1.44269504f;
    const bool isb = (*flagp != 0);
    const int id = blockIdx.x;                // 0..4095
    const int xcd = id & 7;
    const int slot = id >> 3;                 // 0..511
    const int qslot = slot & 63;
    const int q0 = qslot * 32;
    const int v = (slot >> 6) * 8 + xcd;      // 0..63
    const int h = v & 15;
    const int zh = v >> 4;                    // 0..3
    const int z = zh & 1, half = zh >> 1;
    const int t = threadIdx.x;
    const int li = t & 15, quad = t >> 4;

    const int m_h = m >> 1;
    const int jbeg = half * m_h;

    const bf16* qz = qb + (size_t)z * qo_bs;
    const bf16* kb = z ? kv1 : kv0;
    const bf16* vtb = kb + (size_t)m * 1024;

    __shared__ float bias_s[32];
    __shared__ float tab[1088];     // covers m_h+31 <= 1055
    __shared__ bf16 Ps[16][40];

    if (t < 32) bias_s[t] = ldx(rel_emb, t * 16 + h, isb) * SC - 40.0f;
    __syncthreads();

    const int tsz = m_h + 31;
    for (int i = t; i < tsz; i += 64) {
        const int j = jbeg + i;               // global key-ish index
        const int rel = j - 31 - q0 + rel_off;
        const int ab = rel < 0 ? -rel : rel;
        int bucket = rel >= 0 ? 16 : 0;
        if (ab < 8) {
            bucket += ab;
        } else {
            const int p = 31 - __clz(ab);
            const int k2 = 2 * p + ((ab * ab >= (1 << (2 * p + 1))) ? 1 : 0);
            const int val = k2 + 2;
            bucket += (val > 15) ? 15 : val;
        }
        tab[i] = bias_s[bucket];
    }
    __syncthreads();

    bf16x8 aq[2][2];
#pragma unroll
    for (int g = 0; g < 2; g++)
#pragma unroll
        for (int kc = 0; kc < 2; kc++)
            aq[g][kc] = *(const bf16x8*)(qz + (size_t)(q0 + g * 16 + li) * 1024
                                         + h * 64 + kc * 32 + quad * 8);

    bf16x8 ones;
#pragma unroll
    for (int j = 0; j < 8; j++) ((short*)&ones)[j] = 0x3F80;

    f32x4 o[2][4], lac[2];
#pragma unroll
    for (int g = 0; g < 2; g++) {
#pragma unroll
        for (int r = 0; r < 4; r++) lac[g][r] = 0.f;
#pragma unroll
        for (int nb = 0; nb < 4; nb++)
#pragma unroll
            for (int r = 0; r < 4; r++) o[g][nb][r] = 0.f;
    }

    for (int jl = 0; jl < m_h; jl += 32) {    // local key offset in [0, m_h)
        const int j0 = jbeg + jl;             // global key offset
        bf16x8 kf[4], vf[4];
#pragma unroll
        for (int nb = 0; nb < 2; nb++)
#pragma unroll
            for (int kc = 0; kc < 2; kc++)
                kf[nb * 2 + kc] = *(const bf16x8*)(
                    kb + (size_t)(j0 + nb * 16 + li) * 1024 + h * 64 + kc * 32 + quad * 8);
#pragma unroll
        for (int nb = 0; nb < 4; nb++)
            vf[nb] = *(const bf16x8*)(
                vtb + (size_t)(h * 64 + nb * 16 + li) * m + j0 + quad * 8);

#pragma unroll
        for (int g = 0; g < 2; g++) {
            f32x4 s[2];
            __builtin_amdgcn_s_setprio(1);
#pragma unroll
            for (int nb = 0; nb < 2; nb++) {
                f32x4 a;
#pragma unroll
                for (int r = 0; r < 4; r++) a[r] = 0.f;
#pragma unroll
                for (int kc = 0; kc < 2; kc++)
                    a = __builtin_amdgcn_mfma_f32_16x16x32_bf16(aq[g][kc], kf[nb * 2 + kc],
                                                                a, 0, 0, 0);
                s[nb] = a;
            }
            __builtin_amdgcn_s_setprio(0);
#pragma unroll
            for (int nb = 0; nb < 2; nb++)
#pragma unroll
                for (int r = 0; r < 4; r++) {
                    const int ti = jl + nb * 16 + li + 31 - (g * 16 + quad * 4 + r);
                    s[nb][r] = exp2f(fmaf(s[nb][r], SC, tab[ti]));
                }
#pragma unroll
            for (int nb = 0; nb < 2; nb++)
#pragma unroll
                for (int r = 0; r < 4; r++)
                    Ps[quad * 4 + r][nb * 16 + li] = f2b(s[nb][r]);
            const bf16x8 ap = *(const bf16x8*)&Ps[li][quad * 8];
            __builtin_amdgcn_s_setprio(1);
#pragma unroll
            for (int nb = 0; nb < 4; nb++)
                o[g][nb] = __builtin_amdgcn_mfma_f32_16x16x32_bf16(ap, vf[nb],
                                                                   o[g][nb], 0, 0, 0);
            lac[g] = __builtin_amdgcn_mfma_f32_16x16x32_bf16(ap, ones, lac[g], 0, 0, 0);
            __builtin_amdgcn_s_setprio(0);
        }
    }

    // ---- write f32 partials (no divide) ----
    const int pidx = ((z * 2 + half) * 16 + h) * 64 + qslot;    // 0..4095
    float* op = po + (size_t)pidx * 2048;
    float* lp = pl + (size_t)pidx * 32;
#pragma unroll
    for (int g = 0; g < 2; g++)
#pragma unroll
        for (int r = 0; r < 4; r++) {
            const int row = g * 16 + quad * 4 + r;
            if (li == 0) lp[row] = lac[g][r];   // identical across li
#pragma unroll
            for (int nb = 0; nb < 4; nb++)
                op[row * 64 + nb * 16 + li] = o[g][nb][r];
        }
}

// ---------------------------------------------------------------------------
// Combine: out = (O0 + O1) / (l0 + l1). Grid 2048 blocks x 64 threads.
// ---------------------------------------------------------------------------
__global__ __launch_bounds__(64) void attn_comb(
    const float* __restrict__ po, const float* __restrict__ pl,
    bf16* __restrict__ out, long out_bs) {
    const int id = blockIdx.x;            // 0..2047
    const int qslot = id & 63;
    const int v = id >> 6;                // 0..31
    const int h = v & 15, z = v >> 4;
    const int p0 = ((z * 2 + 0) * 16 + h) * 64 + qslot;
    const int p1 = ((z * 2 + 1) * 16 + h) * 64 + qslot;
    const float* o0 = po + (size_t)p0 * 2048;
    const float* o1 = po + (size_t)p1 * 2048;
    const float* l0 = pl + (size_t)p0 * 32;
    const float* l1 = pl + (size_t)p1 * 32;
    bf16* oz = out + (size_t)z * out_bs;
    const int t = threadIdx.x;            // d index 0..63
#pragma unroll 4
    for (int r = 0; r < 32; r++) {
        const float inv = 1.0f / (l0[r] + l1[r]);
        const float val = (o0[r * 64 + t] + o1[r * 64 + t]) * inv;
        oz[(size_t)(qslot * 32 + r) * 1024 + h * 64 + t] = f2b(val);
    }
}

// ---------------------------------------------------------------------------
// Launcher. Fast path (ws >= 96 MB + 256; measured ws = 256 MB):
//   F_A|F_B|F_C (24 MB) + WT (8) + F_X (8) + F_Y (6) + WT2 (8) = 54 MB,
//   then P_O (32 MB f32 partial O) + P_L (0.5 MB partial l).
// Fallback: round-7 plan (24 MB) with unsplit attn_flash.
// ---------------------------------------------------------------------------
extern "C" void kernel_launch(void* const* d_in, const int* in_sizes, int n_in,
                              void* d_out, int out_size, void* d_ws, size_t ws_size,
                              hipStream_t stream) {
    const long M1 = 1024 * 1024;
    const long M2 = 2 * 1024 * 1024;
    const long M4 = 4 * 1024 * 1024;
    if (ws_size < 24u * 1024 * 1024 + 256) return;

    const void* x      = d_in[0];
    const void* ctx    = d_in[1];
    const void* sa_ng  = d_in[2];
    const void* sa_nb  = d_in[3];
    const void* sa_ncg = d_in[4];
    const void* sa_ncb = d_in[5];
    const void* sa_wq  = d_in[6];
    const void* sa_wkv = d_in[7];
    const void* sa_wo  = d_in[8];
    const void* sa_bo  = d_in[9];
    const void* sa_rel = d_in[10];
    const void* ca_ng  = d_in[11];
    const void* ca_nb  = d_in[12];
    const void* ca_ncg = d_in[13];
    const void* ca_ncb = d_in[14];
    const void* ca_wq  = d_in[15];
    const void* ca_wkv = d_in[16];
    const void* ca_wo  = d_in[17];
    const void* ca_bo  = d_in[18];
    const void* ca_rel = d_in[19];

    int* flag = (int*)d_ws;
    bf16* F_A = (bf16*)((char*)d_ws + 256);
    bf16* F_B = F_A + M4;
    bf16* F_C = F_B + M4;
    bf16* WT  = F_C + M4;                // fast path only (SA weights)
    bf16* F_X = WT + M4;                 // fast path only (xn buffer)
    bf16* F_Y = F_X + M4;                // fast path only (ctx-LN + CA K/V)
    bf16* WT2 = F_Y + 3 * M1;            // fast path only (CA weights)
    float* P_O = (float*)(WT2 + M4);     // 4096 x 2048 f32 = 32 MB
    float* P_L = P_O + 4096 * 2048;      // 4096 x 32 f32 = 0.5 MB
    bf16* qd  = (bf16*)d_out;            // d_out as bf16 scratch (q / ao)

    sniff_kernel<<<1, 256, 0, stream>>>(x, flag);

    if (ws_size >= 96u * 1024 * 1024 + 256) {
        bf16* WTq  = WT;                 // [1024][1024]
        bf16* WTkv = WT + M1;            // [2048][1024]
        bf16* WTo  = WT + 3 * M1;        // [1024][1024]
        bf16* WT2q  = WT2;
        bf16* WT2kv = WT2 + M1;
        bf16* WT2o  = WT2 + 3 * M1;
        bf16* CAK0 = F_Y + M1;           // z0: K[512][1024] + V^T[1024][512]
        bf16* CAK1 = F_Y + 2 * M1;       // z1: same layout
        GArgs gz = {};                   // empty slot (nbx = 0)

        // ===== prologue: all weight transposes + both input LNs =====
        wconv8_kernel<<<dim3(16, 16, 8), 256, 0, stream>>>(
            sa_wq, sa_wkv, sa_wo, ca_wq, ca_wkv, ca_wo,
            WTq, WTkv, WTo, WT2q, WT2kv, WT2o, flag);
        ln_dual_kernel<<<dim3(2048, 1, 2), 256, 0, stream>>>(
            x, 0, M2, 1, sa_ng, sa_nb, sa_ncg, sa_ncb, F_X, F_B, M2, flag);
        ln_dual_kernel<<<dim3(512, 1, 2), 256, 0, stream>>>(
            ctx, 0, 512 * 1024, 1, ca_ncg, ca_ncb, nullptr, nullptr,
            F_Y, nullptr, 512 * 1024, flag);

        // ===== BIG: SA-q + SA-kv + CA-kv (all independent) =====
        {
            GArgs gq = {};
            gq.A = F_X; gq.Bt = WTq; gq.C = qd;
            gq.N = 1024; gq.nbx = 8; gq.nby = 32;
            GArgs gkv = {};
            gkv.A = F_B; gkv.Bt = WTkv;
            gkv.N = 2048; gkv.mode = 1; gkv.zsplit = 2048; gkv.zrows = 2048;
            gkv.kb0 = F_A; gkv.kb1 = F_C; gkv.nbx = 16; gkv.nby = 32;
            GArgs gca = {};
            gca.A = F_Y; gca.Bt = WT2kv;
            gca.N = 2048; gca.mode = 1; gca.zsplit = 512; gca.zrows = 512;
            gca.kb0 = CAK0; gca.kb1 = CAK1; gca.nbx = 16; gca.nby = 8;
            gemm_fused<<<dim3(40, 32), 256, 0, stream>>>(gq, gkv, gca, flag);
        }

        // ===== self-attention (key-split) + o-proj =====
        attn_split<<<dim3(4096), 64, 0, stream>>>(
            qd, F_A, F_C, sa_rel, P_O, P_L, M2, 2048, 0, flag);
        attn_comb<<<dim3(2048), 64, 0, stream>>>(P_O, P_L, qd, M2);
        {
            GArgs go = {};
            go.A = qd; go.Bt = WTo; go.C = F_B;
            go.bias = sa_bo; go.res = x; go.res_ext = 1;
            go.N = 1024; go.nbx = 8; go.nby = 32;
            gemm_fused<<<dim3(8, 32), 256, 0, stream>>>(go, gz, gz, flag);
        }

        // ===== cross-attention (key-split) =====
        ln_dual_kernel<<<dim3(2048, 1, 2), 256, 0, stream>>>(
            F_B, 0, M2, 0, ca_ng, ca_nb, nullptr, nullptr, F_X, nullptr, M2, flag);
        {
            GArgs gq = {};
            gq.A = F_X; gq.Bt = WT2q; gq.C = qd;
            gq.N = 1024; gq.nbx = 8; gq.nby = 32;
            gemm_fused<<<dim3(8, 32), 256, 0, stream>>>(gq, gz, gz, flag);
        }
        attn_split<<<dim3(4096), 64, 0, stream>>>(
            qd, CAK0, CAK1, ca_rel, P_O, P_L, M2, 512, 1536, flag);
        attn_comb<<<dim3(2048), 64, 0, stream>>>(P_O, P_L, F_C, M2);
        {
            GArgs go = {};
            go.A = F_C; go.Bt = WT2o; go.C = d_out; go.c_ext = 1;
            go.bias = ca_bo; go.res = F_B;
            go.N = 1024; go.nbx = 8; go.nby = 32;
            gemm_fused<<<dim3(8, 32), 256, 0, stream>>>(go, gz, gz, flag);
        }
        return;
    }

    // ================= fallback: round-7 verified plan =================
    ln_dual_kernel<<<dim3(2048, 1, 2), 256, 0, stream>>>(
        x, 0, M2, 1, sa_ng, sa_nb, sa_ncg, sa_ncb, F_A, F_B, M2, flag);
    gemm_mfma<<<dim3(16, 32, 2), 256, 0, stream>>>(
        F_A, M2, sa_wq, qd, 0, M2, 0, nullptr, nullptr, 0, 0, 0,
        1024, 1024, 0, 0, nullptr, nullptr, flag);
    gemm_mfma<<<dim3(32, 32, 2), 256, 0, stream>>>(
        F_B, M2, sa_wkv, nullptr, 0, 0, 0, nullptr, nullptr, 0, 0, 0,
        1024, 2048, 1, 2048, F_A, F_C, flag);
    attn_flash<<<dim3(2048), 64, 0, stream>>>(
        qd, F_A, F_C, sa_rel, qd, M2, M2, 2048, 0, flag);
    gemm_mfma<<<dim3(16, 32, 2), 256, 0, stream>>>(
        qd, M2, sa_wo, F_B, 0, M2, 0, sa_bo, x, 0, M2, 1,
        1024, 1024, 0, 0, nullptr, nullptr, flag);

    ln_dual_kernel<<<dim3(2048, 1, 2), 256, 0, stream>>>(
        F_B, 0, M2, 0, ca_ng, ca_nb, nullptr, nullptr, F_A, nullptr, M2, flag);
    ln_dual_kernel<<<dim3(512, 1, 2), 256, 0, stream>>>(
        ctx, 0, 512 * 1024, 1, ca_ncg, ca_ncb, nullptr, nullptr,
        F_C, nullptr, 512 * 1024, flag);
    gemm_mfma<<<dim3(16, 32, 2), 256, 0, stream>>>(
        F_A, M2, ca_wq, qd, 0, M2, 0, nullptr, nullptr, 0, 0, 0,
        1024, 1024, 0, 0, nullptr, nullptr, flag);
    gemm_mfma<<<dim3(32, 8, 2), 256, 0, stream>>>(
        F_C, 512 * 1024, ca_wkv, nullptr, 0, 0, 0, nullptr, nullptr, 0, 0, 0,
        1024, 2048, 1, 512, F_A, F_A + M1, flag);
    attn_flash<<<dim3(2048), 64, 0, stream>>>(
        qd, F_A, F_A + M1, ca_rel, F_C, M2, M2, 512, 1536, flag);
    gemm_mfma<<<dim3(16, 32, 2), 256, 0, stream>>>(
        F_C, M2, ca_wo, d_out, 0, M2, 1, ca_bo, F_B, 0, M2, 0,
        1024, 1024, 0, 0, nullptr, nullptr, flag);
}

// Round 7
// 494.604 us; speedup vs baseline: 1.0879x; 1.0879x over previous
//
#include <hip/hip_runtime.h>
#include <hip/hip_bf16.h>

typedef __hip_bfloat16 bf16;
typedef __attribute__((ext_vector_type(8))) short bf16x8;   // 8 bf16 (4 VGPRs)
typedef __attribute__((ext_vector_type(4))) float f32x4;    // MFMA accum

__device__ __forceinline__ float b2f(bf16 v) { return __bfloat162float(v); }
__device__ __forceinline__ bf16 f2b(float v) { return __float2bfloat16(v); }

// Scalar load/store from an external buffer whose dtype is decided by isb.
__device__ __forceinline__ float ldx(const void* p, size_t i, bool isb) {
    return isb ? b2f(((const bf16*)p)[i]) : ((const float*)p)[i];
}
__device__ __forceinline__ void stx(void* p, size_t i, bool isb, float v) {
    if (isb) ((bf16*)p)[i] = f2b(v);
    else     ((float*)p)[i] = v;
}
// Vector (8-elem) external load; i must be a multiple of 8.
__device__ __forceinline__ void ldx8(const void* p, size_t i, bool isb, float* o) {
    if (isb) {
        const bf16x8 v = *(const bf16x8*)((const bf16*)p + i);
#pragma unroll
        for (int j = 0; j < 8; j++) o[j] = b2f(((const bf16*)&v)[j]);
    } else {
        const float4 v0 = *(const float4*)((const float*)p + i);
        const float4 v1 = *(const float4*)((const float*)p + i + 4);
        o[0]=v0.x; o[1]=v0.y; o[2]=v0.z; o[3]=v0.w;
        o[4]=v1.x; o[5]=v1.y; o[6]=v1.z; o[7]=v1.w;
    }
}

// Async global->LDS 16B copy (m97 path). LDS dest = wave-uniform base +
// lane*16 (HW semantics, m104); global src is per-lane; size literal 16.
__device__ __forceinline__ void glds16(const void* g, void* l) {
    __builtin_amdgcn_global_load_lds(
        (const __attribute__((address_space(1))) void*)g,
        (__attribute__((address_space(3))) void*)l, 16, 0, 0);
}

// ---------------------------------------------------------------------------
// Dtype sniffer (verified round 3): decides fp32 vs bf16 external data.
// ---------------------------------------------------------------------------
__global__ void sniff_kernel(const void* __restrict__ x, int* __restrict__ flag) {
    const unsigned* w = (const unsigned*)x;
    const int t = threadIdx.x;
    int cnt = 0;
#pragma unroll
    for (int i = 0; i < 4; i++) {
        const unsigned word = w[t * 4 + i];
        const int e = (word >> 23) & 0xFF;
        cnt += (e >= 192) ? 1 : 0;
    }
    __shared__ int red[4];
#pragma unroll
    for (int o = 32; o > 0; o >>= 1) cnt += __shfl_down(cnt, o);
    if ((t & 63) == 0) red[t >> 6] = cnt;
    __syncthreads();
    if (t == 0) flag[0] = ((red[0] + red[1] + red[2] + red[3]) >= 512) ? 1 : 0;
}

// ---------------------------------------------------------------------------
// Merged weight convert+transpose for BOTH attention phases in one dispatch:
// grid (16,16,8): z 0..3 = SA {wq, wkv-lo, wkv-hi, wo} -> WT*, z 4..7 = CA
// -> WT2*. 64x64 LDS-tiled transpose, K=1024 for all.
// ---------------------------------------------------------------------------
__global__ void wconv8_kernel(const void* __restrict__ Wq,
                              const void* __restrict__ Wkv,
                              const void* __restrict__ Wo,
                              const void* __restrict__ Wq2,
                              const void* __restrict__ Wkv2,
                              const void* __restrict__ Wo2,
                              bf16* __restrict__ WTq, bf16* __restrict__ WTkv,
                              bf16* __restrict__ WTo,
                              bf16* __restrict__ WTq2, bf16* __restrict__ WTkv2,
                              bf16* __restrict__ WTo2,
                              const int* __restrict__ flagp) {
    const bool isb = (*flagp != 0);
    const int z = blockIdx.z;
    const int zz = z & 3;
    const bool ca = z >= 4;
    const void* W = ca ? ((zz == 0) ? Wq2 : (zz == 3) ? Wo2 : Wkv2)
                       : ((zz == 0) ? Wq  : (zz == 3) ? Wo  : Wkv);
    bf16* Wt      = ca ? ((zz == 0) ? WTq2 : (zz == 3) ? WTo2 : WTkv2)
                       : ((zz == 0) ? WTq  : (zz == 3) ? WTo  : WTkv);
    const int N   = (zz == 1 || zz == 2) ? 2048 : 1024;
    const int K = 1024;
    __shared__ float T[64][65];
    const int n0 = blockIdx.x * 64 + ((zz == 2) ? 1024 : 0);
    const int k0 = blockIdx.y * 64;
    const int t = threadIdx.x;
    const int rr = t >> 3, c8 = (t & 7) * 8;
#pragma unroll
    for (int i = 0; i < 2; i++) {
        const int row = rr + i * 32;
        float v[8];
        ldx8(W, (size_t)(k0 + row) * N + n0 + c8, isb, v);
#pragma unroll
        for (int j = 0; j < 8; j++) T[row][c8 + j] = v[j];
    }
    __syncthreads();
#pragma unroll
    for (int i = 0; i < 2; i++) {
        const int row = rr + i * 32;   // n-index within tile
        bf16x8 ov;
#pragma unroll
        for (int j = 0; j < 8; j++) ((bf16*)&ov)[j] = f2b(T[c8 + j][row]);
        *(bf16x8*)(Wt + (size_t)(n0 + row) * K + k0 + c8) = ov;
    }
}

// ---------------------------------------------------------------------------
// LayerNorm over F=1024, batch-fused via grid.z (per-batch strides in elems).
// ---------------------------------------------------------------------------
__global__ void ln_dual_kernel(const void* __restrict__ in, size_t in_off, long in_bs,
                               int in_ext,
                               const void* __restrict__ g1, const void* __restrict__ b1,
                               const void* __restrict__ g2, const void* __restrict__ b2,
                               bf16* __restrict__ out1, bf16* __restrict__ out2,
                               long out_bs, const int* __restrict__ flagp) {
    const int F = 1024;
    const bool isb = (*flagp != 0);
    const bool inb = in_ext ? isb : true;
    const int row = blockIdx.x;
    const int z = blockIdx.z;
    const int t = threadIdx.x;
    const size_t base = in_off + (size_t)z * in_bs + (size_t)row * F;
    const size_t obase = (size_t)z * out_bs + (size_t)row * F;

    float v[4];
    float s = 0.f;
#pragma unroll
    for (int i = 0; i < 4; i++) { v[i] = ldx(in, base + t + 256 * i, inb); s += v[i]; }

    __shared__ float red1[4];
    __shared__ float red2[4];
#pragma unroll
    for (int o = 32; o > 0; o >>= 1) s += __shfl_down(s, o);
    if ((t & 63) == 0) red1[t >> 6] = s;
    __syncthreads();
    const float mean = (red1[0] + red1[1] + red1[2] + red1[3]) * (1.0f / F);

    float ss = 0.f;
#pragma unroll
    for (int i = 0; i < 4; i++) { float d = v[i] - mean; ss += d * d; }
#pragma unroll
    for (int o = 32; o > 0; o >>= 1) ss += __shfl_down(ss, o);
    if ((t & 63) == 0) red2[t >> 6] = ss;
    __syncthreads();
    const float var = (red2[0] + red2[1] + red2[2] + red2[3]) * (1.0f / F);
    const float rn = rsqrtf(var + 1e-5f);

#pragma unroll
    for (int i = 0; i < 4; i++) {
        const int idx = t + 256 * i;
        const float nv = (v[i] - mean) * rn;
        out1[obase + idx] = f2b(nv * ldx(g1, idx, isb) + ldx(b1, idx, isb));
        if (out2) out2[obase + idx] = f2b(nv * ldx(g2, idx, isb) + ldx(b2, idx, isb));
    }
}

// ---------------------------------------------------------------------------
// Grouped GEMM args. C = A[R,1024] @ Bt^T, 128x128 tile, BK=64, 4 waves.
// ---------------------------------------------------------------------------
struct GArgs {
    const bf16* A; const bf16* Bt; void* C;
    const void* bias; const void* res;
    bf16* kb0; bf16* kb1;
    int c_ext, res_ext, N, mode, zsplit, zrows, nbx, nby;
};

// Shared epilogue for both GEMM bodies.
#define GEMM_EPILOGUE                                                          \
    if (g.mode == 1) {                                                         \
        _Pragma("unroll")                                                      \
        for (int mi = 0; mi < 4; mi++)                                         \
            _Pragma("unroll")                                                  \
            for (int r = 0; r < 4; r++) {                                      \
                const int row = bm + wm + mi * 16 + quad * 4 + r;              \
                bf16* kb = (row < g.zsplit) ? g.kb0 : g.kb1;                   \
                const int lrow = (row < g.zsplit) ? row : row - g.zsplit;      \
                _Pragma("unroll")                                              \
                for (int ni = 0; ni < 4; ni++) {                               \
                    const int col = bn + wn + ni * 16 + li;                    \
                    const float v = acc[mi][ni][r];                            \
                    if (col < 1024)                                            \
                        kb[(size_t)lrow * 1024 + col] = f2b(v);                \
                    else                                                       \
                        kb[(size_t)1024 * g.zrows                              \
                           + (size_t)(col - 1024) * g.zrows + lrow] = f2b(v);  \
                }                                                              \
            }                                                                  \
        return;                                                                \
    }                                                                          \
    _Pragma("unroll")                                                          \
    for (int mi = 0; mi < 4; mi++)                                             \
        _Pragma("unroll")                                                      \
        for (int r = 0; r < 4; r++) {                                          \
            const int row = bm + wm + mi * 16 + quad * 4 + r;                  \
            _Pragma("unroll")                                                  \
            for (int ni = 0; ni < 4; ni++) {                                   \
                const int col = bn + wn + ni * 16 + li;                        \
                float v = acc[mi][ni][r];                                      \
                if (g.bias) v += ldx(g.bias, col, isb);                        \
                if (g.res)  v += ldx(g.res, (size_t)row * g.N + col,           \
                                     g.res_ext ? isb : true);                  \
                stx(g.C, (size_t)row * g.N + col, g.c_ext ? isb : true, v);    \
            }                                                                  \
        }

// ---------------------------------------------------------------------------
// Reg-staged grouped GEMM (round-0 verified body, padded LDS). Used for the
// SMALL dispatches (1 block/CU, where round 2 showed async staging loses).
// ---------------------------------------------------------------------------
__global__ __launch_bounds__(256) void gemm_fused(GArgs ga, GArgs gb, GArgs gc,
                                                  const int* __restrict__ flagp) {
    int bx = (int)blockIdx.x;
    GArgs g;
    if (bx < ga.nbx) { g = ga; }
    else if (bx < ga.nbx + gb.nbx) { g = gb; bx -= ga.nbx; }
    else { g = gc; bx -= ga.nbx + gb.nbx; }
    const int by = (int)blockIdx.y;
    if (by >= g.nby) return;               // block-uniform: no divergent barrier

    const int K = 1024;
    const bool isb = (*flagp != 0);

    __shared__ bf16 As[128][72];
    __shared__ bf16 Bs[128][72];

    const int t = threadIdx.x;
    const int w = t >> 6, lane = t & 63, li = lane & 15, quad = lane >> 4;
    const int wm = (w & 1) * 64, wn = (w >> 1) * 64;
    const int bm = by * 128, bn = bx * 128;

    f32x4 acc[4][4];
#pragma unroll
    for (int mi = 0; mi < 4; mi++)
#pragma unroll
        for (int ni = 0; ni < 4; ni++)
#pragma unroll
            for (int r = 0; r < 4; r++) acc[mi][ni][r] = 0.f;

    for (int k0 = 0; k0 < K; k0 += 64) {
#pragma unroll
        for (int c = 0; c < 4; c++) {
            const int d = c * 256 + t;
            const int row = d >> 3, ch = (d & 7) * 8;
            *(bf16x8*)&As[row][ch] = *(const bf16x8*)(g.A + (size_t)(bm + row) * K + k0 + ch);
            *(bf16x8*)&Bs[row][ch] = *(const bf16x8*)(g.Bt + (size_t)(bn + row) * K + k0 + ch);
        }
        __syncthreads();
#pragma unroll
        for (int kc = 0; kc < 2; kc++) {
            bf16x8 af[4], bfr[4];
#pragma unroll
            for (int i = 0; i < 4; i++) {
                af[i]  = *(const bf16x8*)&As[wm + i * 16 + li][kc * 32 + quad * 8];
                bfr[i] = *(const bf16x8*)&Bs[wn + i * 16 + li][kc * 32 + quad * 8];
            }
#pragma unroll
            for (int mi = 0; mi < 4; mi++)
#pragma unroll
                for (int ni = 0; ni < 4; ni++)
                    acc[mi][ni] = __builtin_amdgcn_mfma_f32_16x16x32_bf16(
                        af[mi], bfr[ni], acc[mi][ni], 0, 0, 0);
        }
        __syncthreads();
    }

    GEMM_EPILOGUE
}

// ---------------------------------------------------------------------------
// ROUND 7: m97-structure grouped GEMM for the BIG dispatch (3.5 blocks/CU —
// the regime where global_load_lds width-16 measured 874 vs 646 TF reg-staged
// at this exact 128^2/BK=64 tile, m151/m97). Single-buffered LINEAR LDS
// [128][64] (glds dest must be wave-uniform+lane*16 -> no pad), 2 barriers
// per K-step. 16-way ds_read conflicts accepted (m98: 1.7e7 conflicts at 874
// TF — hidden by inter-block overlap, which THIS dispatch has; round 2's
// regression was applying it at 1-2 blocks/CU where it isn't).
// ---------------------------------------------------------------------------
__global__ __launch_bounds__(256) void gemm_fused_lds(GArgs ga, GArgs gb, GArgs gc,
                                                      const int* __restrict__ flagp) {
    int bx = (int)blockIdx.x;
    GArgs g;
    if (bx < ga.nbx) { g = ga; }
    else if (bx < ga.nbx + gb.nbx) { g = gb; bx -= ga.nbx; }
    else { g = gc; bx -= ga.nbx + gb.nbx; }
    const int by = (int)blockIdx.y;
    if (by >= g.nby) return;               // block-uniform: no divergent barrier

    const int K = 1024;
    const bool isb = (*flagp != 0);

    __shared__ bf16 As[128][64];           // linear: glds requires contiguity
    __shared__ bf16 Bs[128][64];

    const int t = threadIdx.x;
    const int w = t >> 6, lane = t & 63, li = lane & 15, quad = lane >> 4;
    const int wm = (w & 1) * 64, wn = (w >> 1) * 64;
    const int bm = by * 128, bn = bx * 128;
    const int srow = t >> 3;               // 0..31 (row within 32-row chunk)
    const int sch  = (t & 7) * 8;          // k-offset, 8 bf16 = 16 B

    f32x4 acc[4][4];
#pragma unroll
    for (int mi = 0; mi < 4; mi++)
#pragma unroll
        for (int ni = 0; ni < 4; ni++)
#pragma unroll
            for (int r = 0; r < 4; r++) acc[mi][ni][r] = 0.f;

    for (int k0 = 0; k0 < K; k0 += 64) {
        // async stage: thread t, chunk c covers LDS element (c*256+t)*8 ==
        // row (c*32+srow), col sch. Wave base = (c*256 + w*64)*16 bytes.
#pragma unroll
        for (int c = 0; c < 4; c++) {
            glds16(g.A + (size_t)(bm + c * 32 + srow) * K + k0 + sch,
                   (char*)&As[0][0] + (size_t)(c * 256 + w * 64) * 16);
            glds16(g.Bt + (size_t)(bn + c * 32 + srow) * K + k0 + sch,
                   (char*)&Bs[0][0] + (size_t)(c * 256 + w * 64) * 16);
        }
        __syncthreads();                   // barrier lowering drains vmcnt(0)
#pragma unroll
        for (int kc = 0; kc < 2; kc++) {
            bf16x8 af[4], bfr[4];
#pragma unroll
            for (int i = 0; i < 4; i++) {
                af[i]  = *(const bf16x8*)&As[wm + i * 16 + li][kc * 32 + quad * 8];
                bfr[i] = *(const bf16x8*)&Bs[wn + i * 16 + li][kc * 32 + quad * 8];
            }
#pragma unroll
            for (int mi = 0; mi < 4; mi++)
#pragma unroll
                for (int ni = 0; ni < 4; ni++)
                    acc[mi][ni] = __builtin_amdgcn_mfma_f32_16x16x32_bf16(
                        af[mi], bfr[ni], acc[mi][ni], 0, 0, 0);
        }
        __syncthreads();
    }

    GEMM_EPILOGUE
}

// ---------------------------------------------------------------------------
// Slow-path MFMA GEMM (round-7 verified, used only if workspace is small).
// ---------------------------------------------------------------------------
__global__ __launch_bounds__(256) void gemm_mfma(
    const bf16* __restrict__ A, long a_bs, const void* __restrict__ W,
    void* __restrict__ C, size_t c_off, long c_bs, int c_ext,
    const void* __restrict__ bias,
    const void* __restrict__ res, size_t res_off, long res_bs, int res_ext,
    int K, int N, int mode, int R,
    bf16* __restrict__ kb0, bf16* __restrict__ kb1,
    const int* __restrict__ flagp) {

    const bool isb = (*flagp != 0);
    const bool resb = res_ext ? isb : true;
    const bool cb = c_ext ? isb : true;
    const int z = blockIdx.z;

    const bf16* Az = A + (size_t)z * a_bs;
    const size_t coz = c_off + (size_t)z * c_bs;
    const size_t roz = res_off + (size_t)z * res_bs;

    __shared__ bf16 As[64][72];
    __shared__ bf16 Bs[64][72];

    const int t = threadIdx.x;
    const int w = t >> 6, lane = t & 63, li = lane & 15, quad = lane >> 4;
    const int wm = (w & 1) * 32, wn = (w >> 1) * 32;
    const int bm = blockIdx.y * 64, bn = blockIdx.x * 64;

    f32x4 acc[2][2];
#pragma unroll
    for (int mi = 0; mi < 2; mi++)
#pragma unroll
        for (int ni = 0; ni < 2; ni++)
#pragma unroll
            for (int r = 0; r < 4; r++) acc[mi][ni][r] = 0.f;

    for (int k0 = 0; k0 < K; k0 += 64) {
#pragma unroll
        for (int c = 0; c < 2; c++) {
            const int lin = t * 16 + c * 8;
            const int row = lin >> 6, kk = lin & 63;
            *(bf16x8*)&As[row][kk] = *(const bf16x8*)(Az + (size_t)(bm + row) * K + k0 + kk);
        }
#pragma unroll
        for (int c = 0; c < 2; c++) {
            const int lin = t * 16 + c * 8;
            const int kk = lin >> 6, n0 = lin & 63;
            float v[8];
            ldx8(W, (size_t)(k0 + kk) * N + bn + n0, isb, v);
            const int st = t & 7;
#pragma unroll
            for (int i = 0; i < 8; i++) {
                const int ii = (i + st) & 7;
                Bs[n0 + ii][kk] = f2b(v[ii]);
            }
        }
        __syncthreads();
#pragma unroll
        for (int kc = 0; kc < 2; kc++) {
            bf16x8 af[2], bfr[2];
#pragma unroll
            for (int mi = 0; mi < 2; mi++)
                af[mi] = *(const bf16x8*)&As[wm + mi * 16 + li][kc * 32 + quad * 8];
#pragma unroll
            for (int ni = 0; ni < 2; ni++)
                bfr[ni] = *(const bf16x8*)&Bs[wn + ni * 16 + li][kc * 32 + quad * 8];
#pragma unroll
            for (int mi = 0; mi < 2; mi++)
#pragma unroll
                for (int ni = 0; ni < 2; ni++)
                    acc[mi][ni] = __builtin_amdgcn_mfma_f32_16x16x32_bf16(
                        af[mi], bfr[ni], acc[mi][ni], 0, 0, 0);
        }
        __syncthreads();
    }

    if (mode == 1) {
        bf16* kb = z ? kb1 : kb0;
#pragma unroll
        for (int mi = 0; mi < 2; mi++)
#pragma unroll
            for (int r = 0; r < 4; r++) {
                const int row = bm + wm + mi * 16 + quad * 4 + r;
#pragma unroll
                for (int ni = 0; ni < 2; ni++) {
                    const int col = bn + wn + ni * 16 + li;
                    const float v = acc[mi][ni][r];
                    if (col < 1024)
                        kb[(size_t)row * 1024 + col] = f2b(v);
                    else
                        kb[(size_t)1024 * R + (size_t)(col - 1024) * R + row] = f2b(v);
                }
            }
        return;
    }

#pragma unroll
    for (int mi = 0; mi < 2; mi++)
#pragma unroll
        for (int r = 0; r < 4; r++) {
            const int row = bm + wm + mi * 16 + quad * 4 + r;
#pragma unroll
            for (int ni = 0; ni < 2; ni++) {
                const int col = bn + wn + ni * 16 + li;
                float v = acc[mi][ni][r];
                if (bias) v += ldx(bias, col, isb);
                if (res)  v += ldx(res, roz + (size_t)row * N + col, resb);
                stx(C, coz + (size_t)row * N + col, cb, v);
            }
        }
}

// ---------------------------------------------------------------------------
// attn_flash: round-0 verified body — best measured (134.6 µs SA). Four
// variants (2-wave split, prefetch, per-g Ps, block key-split) all failed;
// occupancy is pinned ~8 waves/CU by a per-CU limiter regardless of grid.
// This is the attn local optimum; frozen.
// ---------------------------------------------------------------------------
__global__ __launch_bounds__(64) void attn_flash(
    const bf16* __restrict__ qb, const bf16* __restrict__ kv0,
    const bf16* __restrict__ kv1,
    const void* __restrict__ rel_emb, bf16* __restrict__ out,
    long qo_bs, long out_bs, int m, int rel_off, const int* __restrict__ flagp) {

    const float SC = 0.125f * 1.44269504f;
    const bool isb = (*flagp != 0);
    const int id = blockIdx.x;
    const int xcd = id & 7;
    const int slot = id >> 3;
    const int c = (slot >> 6) * 8 + xcd;
    const int h = c & 15, z = c >> 4;
    const int q0 = (slot & 63) * 32;
    const int t = threadIdx.x;
    const int li = t & 15, quad = t >> 4;

    const bf16* qz = qb + (size_t)z * qo_bs;
    bf16* oz = out + (size_t)z * out_bs;
    const bf16* kb = z ? kv1 : kv0;
    const bf16* vtb = kb + (size_t)m * 1024;

    __shared__ float bias_s[32];
    __shared__ float tab[2080];
    __shared__ bf16 Ps[16][40];

    if (t < 32) bias_s[t] = ldx(rel_emb, t * 16 + h, isb) * SC - 40.0f;
    __syncthreads();

    const int tsz = m + 31;
    for (int i = t; i < tsz; i += 64) {
        const int rel = i - 31 - q0 + rel_off;
        const int ab = rel < 0 ? -rel : rel;
        int bucket = rel >= 0 ? 16 : 0;
        if (ab < 8) {
            bucket += ab;
        } else {
            const int p = 31 - __clz(ab);
            const int k2 = 2 * p + ((ab * ab >= (1 << (2 * p + 1))) ? 1 : 0);
            const int val = k2 + 2;
            bucket += (val > 15) ? 15 : val;
        }
        tab[i] = bias_s[bucket];
    }
    __syncthreads();

    bf16x8 aq[2][2];
#pragma unroll
    for (int g = 0; g < 2; g++)
#pragma unroll
        for (int kc = 0; kc < 2; kc++)
            aq[g][kc] = *(const bf16x8*)(qz + (size_t)(q0 + g * 16 + li) * 1024
                                         + h * 64 + kc * 32 + quad * 8);

    bf16x8 ones;
#pragma unroll
    for (int j = 0; j < 8; j++) ((short*)&ones)[j] = 0x3F80;

    f32x4 o[2][4], lac[2];
#pragma unroll
    for (int g = 0; g < 2; g++) {
#pragma unroll
        for (int r = 0; r < 4; r++) lac[g][r] = 0.f;
#pragma unroll
        for (int nb = 0; nb < 4; nb++)
#pragma unroll
            for (int r = 0; r < 4; r++) o[g][nb][r] = 0.f;
    }

    for (int j0 = 0; j0 < m; j0 += 32) {
        bf16x8 kf[4], vf[4];
#pragma unroll
        for (int nb = 0; nb < 2; nb++)
#pragma unroll
            for (int kc = 0; kc < 2; kc++)
                kf[nb * 2 + kc] = *(const bf16x8*)(
                    kb + (size_t)(j0 + nb * 16 + li) * 1024 + h * 64 + kc * 32 + quad * 8);
#pragma unroll
        for (int nb = 0; nb < 4; nb++)
            vf[nb] = *(const bf16x8*)(
                vtb + (size_t)(h * 64 + nb * 16 + li) * m + j0 + quad * 8);

#pragma unroll
        for (int g = 0; g < 2; g++) {
            f32x4 s[2];
            __builtin_amdgcn_s_setprio(1);
#pragma unroll
            for (int nb = 0; nb < 2; nb++) {
                f32x4 a;
#pragma unroll
                for (int r = 0; r < 4; r++) a[r] = 0.f;
#pragma unroll
                for (int kc = 0; kc < 2; kc++)
                    a = __builtin_amdgcn_mfma_f32_16x16x32_bf16(aq[g][kc], kf[nb * 2 + kc],
                                                                a, 0, 0, 0);
                s[nb] = a;
            }
            __builtin_amdgcn_s_setprio(0);
#pragma unroll
            for (int nb = 0; nb < 2; nb++)
#pragma unroll
                for (int r = 0; r < 4; r++) {
                    const int ti = j0 + nb * 16 + li + 31 - (g * 16 + quad * 4 + r);
                    s[nb][r] = exp2f(fmaf(s[nb][r], SC, tab[ti]));
                }
#pragma unroll
            for (int nb = 0; nb < 2; nb++)
#pragma unroll
                for (int r = 0; r < 4; r++)
                    Ps[quad * 4 + r][nb * 16 + li] = f2b(s[nb][r]);
            const bf16x8 ap = *(const bf16x8*)&Ps[li][quad * 8];
            __builtin_amdgcn_s_setprio(1);
#pragma unroll
            for (int nb = 0; nb < 4; nb++)
                o[g][nb] = __builtin_amdgcn_mfma_f32_16x16x32_bf16(ap, vf[nb],
                                                                   o[g][nb], 0, 0, 0);
            lac[g] = __builtin_amdgcn_mfma_f32_16x16x32_bf16(ap, ones, lac[g], 0, 0, 0);
            __builtin_amdgcn_s_setprio(0);
        }
    }

#pragma unroll
    for (int g = 0; g < 2; g++)
#pragma unroll
        for (int r = 0; r < 4; r++) {
            const float inv = 1.0f / lac[g][r];
            const int qi = q0 + g * 16 + quad * 4 + r;
#pragma unroll
            for (int nb = 0; nb < 4; nb++)
                oz[(size_t)qi * 1024 + h * 64 + nb * 16 + li] = f2b(o[g][nb][r] * inv);
        }
}

// ---------------------------------------------------------------------------
// Launcher. Fast path (ws >= 56 MB + 256; measured ws = 256 MB):
//   F_A|F_B|F_C (24 MB) + WT (8) + F_X (8) + F_Y (6) + WT2 (8) = 54 MB.
// Round-5 schedule (489 µs) + attn reverted to round-0 body + big GEMM on
// the m97 glds body. Fallback: round-7 plan (24 MB).
// ---------------------------------------------------------------------------
extern "C" void kernel_launch(void* const* d_in, const int* in_sizes, int n_in,
                              void* d_out, int out_size, void* d_ws, size_t ws_size,
                              hipStream_t stream) {
    const long M1 = 1024 * 1024;
    const long M2 = 2 * 1024 * 1024;
    const long M4 = 4 * 1024 * 1024;
    if (ws_size < 24u * 1024 * 1024 + 256) return;

    const void* x      = d_in[0];
    const void* ctx    = d_in[1];
    const void* sa_ng  = d_in[2];
    const void* sa_nb  = d_in[3];
    const void* sa_ncg = d_in[4];
    const void* sa_ncb = d_in[5];
    const void* sa_wq  = d_in[6];
    const void* sa_wkv = d_in[7];
    const void* sa_wo  = d_in[8];
    const void* sa_bo  = d_in[9];
    const void* sa_rel = d_in[10];
    const void* ca_ng  = d_in[11];
    const void* ca_nb  = d_in[12];
    const void* ca_ncg = d_in[13];
    const void* ca_ncb = d_in[14];
    const void* ca_wq  = d_in[15];
    const void* ca_wkv = d_in[16];
    const void* ca_wo  = d_in[17];
    const void* ca_bo  = d_in[18];
    const void* ca_rel = d_in[19];

    int* flag = (int*)d_ws;
    bf16* F_A = (bf16*)((char*)d_ws + 256);
    bf16* F_B = F_A + M4;
    bf16* F_C = F_B + M4;
    bf16* WT  = F_C + M4;                // fast path only (SA weights)
    bf16* F_X = WT + M4;                 // fast path only (xn buffer)
    bf16* F_Y = F_X + M4;                // fast path only (ctx-LN + CA K/V)
    bf16* WT2 = F_Y + 3 * M1;            // fast path only (CA weights)
    bf16* qd  = (bf16*)d_out;            // d_out as bf16 scratch (q / ao)

    sniff_kernel<<<1, 256, 0, stream>>>(x, flag);

    if (ws_size >= 56u * 1024 * 1024 + 256) {
        bf16* WTq  = WT;                 // [1024][1024]
        bf16* WTkv = WT + M1;            // [2048][1024]
        bf16* WTo  = WT + 3 * M1;        // [1024][1024]
        bf16* WT2q  = WT2;
        bf16* WT2kv = WT2 + M1;
        bf16* WT2o  = WT2 + 3 * M1;
        bf16* CAK0 = F_Y + M1;           // z0: K[512][1024] + V^T[1024][512]
        bf16* CAK1 = F_Y + 2 * M1;       // z1: same layout
        GArgs gz = {};                   // empty slot (nbx = 0)

        // ===== prologue: all weight transposes + both input LNs =====
        wconv8_kernel<<<dim3(16, 16, 8), 256, 0, stream>>>(
            sa_wq, sa_wkv, sa_wo, ca_wq, ca_wkv, ca_wo,
            WTq, WTkv, WTo, WT2q, WT2kv, WT2o, flag);
        ln_dual_kernel<<<dim3(2048, 1, 2), 256, 0, stream>>>(
            x, 0, M2, 1, sa_ng, sa_nb, sa_ncg, sa_ncb, F_X, F_B, M2, flag);
        ln_dual_kernel<<<dim3(512, 1, 2), 256, 0, stream>>>(
            ctx, 0, 512 * 1024, 1, ca_ncg, ca_ncb, nullptr, nullptr,
            F_Y, nullptr, 512 * 1024, flag);

        // ===== BIG (m97 glds body, 3.5 blocks/CU): SA-q + SA-kv + CA-kv ====
        {
            GArgs gq = {};
            gq.A = F_X; gq.Bt = WTq; gq.C = qd;
            gq.N = 1024; gq.nbx = 8; gq.nby = 32;
            GArgs gkv = {};
            gkv.A = F_B; gkv.Bt = WTkv;
            gkv.N = 2048; gkv.mode = 1; gkv.zsplit = 2048; gkv.zrows = 2048;
            gkv.kb0 = F_A; gkv.kb1 = F_C; gkv.nbx = 16; gkv.nby = 32;
            GArgs gca = {};
            gca.A = F_Y; gca.Bt = WT2kv;
            gca.N = 2048; gca.mode = 1; gca.zsplit = 512; gca.zrows = 512;
            gca.kb0 = CAK0; gca.kb1 = CAK1; gca.nbx = 16; gca.nby = 8;
            gemm_fused_lds<<<dim3(40, 32), 256, 0, stream>>>(gq, gkv, gca, flag);
        }

        // ===== self-attention + o-proj =====
        attn_flash<<<dim3(2048), 64, 0, stream>>>(
            qd, F_A, F_C, sa_rel, qd, M2, M2, 2048, 0, flag);
        {
            GArgs go = {};
            go.A = qd; go.Bt = WTo; go.C = F_B;
            go.bias = sa_bo; go.res = x; go.res_ext = 1;
            go.N = 1024; go.nbx = 8; go.nby = 32;
            gemm_fused<<<dim3(8, 32), 256, 0, stream>>>(go, gz, gz, flag);
        }

        // ===== cross-attention =====
        ln_dual_kernel<<<dim3(2048, 1, 2), 256, 0, stream>>>(
            F_B, 0, M2, 0, ca_ng, ca_nb, nullptr, nullptr, F_X, nullptr, M2, flag);
        {
            GArgs gq = {};
            gq.A = F_X; gq.Bt = WT2q; gq.C = qd;
            gq.N = 1024; gq.nbx = 8; gq.nby = 32;
            gemm_fused<<<dim3(8, 32), 256, 0, stream>>>(gq, gz, gz, flag);
        }
        attn_flash<<<dim3(2048), 64, 0, stream>>>(
            qd, CAK0, CAK1, ca_rel, F_C, M2, M2, 512, 1536, flag);
        {
            GArgs go = {};
            go.A = F_C; go.Bt = WT2o; go.C = d_out; go.c_ext = 1;
            go.bias = ca_bo; go.res = F_B;
            go.N = 1024; go.nbx = 8; go.nby = 32;
            gemm_fused<<<dim3(8, 32), 256, 0, stream>>>(go, gz, gz, flag);
        }
        return;
    }

    // ================= fallback: round-7 verified plan =================
    ln_dual_kernel<<<dim3(2048, 1, 2), 256, 0, stream>>>(
        x, 0, M2, 1, sa_ng, sa_nb, sa_ncg, sa_ncb, F_A, F_B, M2, flag);
    gemm_mfma<<<dim3(16, 32, 2), 256, 0, stream>>>(
        F_A, M2, sa_wq, qd, 0, M2, 0, nullptr, nullptr, 0, 0, 0,
        1024, 1024, 0, 0, nullptr, nullptr, flag);
    gemm_mfma<<<dim3(32, 32, 2), 256, 0, stream>>>(
        F_B, M2, sa_wkv, nullptr, 0, 0, 0, nullptr, nullptr, 0, 0, 0,
        1024, 2048, 1, 2048, F_A, F_C, flag);
    attn_flash<<<dim3(2048), 64, 0, stream>>>(
        qd, F_A, F_C, sa_rel, qd, M2, M2, 2048, 0, flag);
    gemm_mfma<<<dim3(16, 32, 2), 256, 0, stream>>>(
        qd, M2, sa_wo, F_B, 0, M2, 0, sa_bo, x, 0, M2, 1,
        1024, 1024, 0, 0, nullptr, nullptr, flag);

    ln_dual_kernel<<<dim3(2048, 1, 2), 256, 0, stream>>>(
        F_B, 0, M2, 0, ca_ng, ca_nb, nullptr, nullptr, F_A, nullptr, M2, flag);
    ln_dual_kernel<<<dim3(512, 1, 2), 256, 0, stream>>>(
        ctx, 0, 512 * 1024, 1, ca_ncg, ca_ncb, nullptr, nullptr,
        F_C, nullptr, 512 * 1024, flag);
    gemm_mfma<<<dim3(16, 32, 2), 256, 0, stream>>>(
        F_A, M2, ca_wq, qd, 0, M2, 0, nullptr, nullptr, 0, 0, 0,
        1024, 1024, 0, 0, nullptr, nullptr, flag);
    gemm_mfma<<<dim3(32, 8, 2), 256, 0, stream>>>(
        F_C, 512 * 1024, ca_wkv, nullptr, 0, 0, 0, nullptr, nullptr, 0, 0, 0,
        1024, 2048, 1, 512, F_A, F_A + M1, flag);
    attn_flash<<<dim3(2048), 64, 0, stream>>>(
        qd, F_A, F_A + M1, ca_rel, F_C, M2, M2, 512, 1536, flag);
    gemm_mfma<<<dim3(16, 32, 2), 256, 0, stream>>>(
        F_C, M2, ca_wo, d_out, 0, M2, 1, ca_bo, F_B, 0, M2, 0,
        1024, 1024, 0, 0, nullptr, nullptr, flag);
}

// Round 8
// 481.875 us; speedup vs baseline: 1.1167x; 1.0264x over previous
//
#include <hip/hip_runtime.h>
#include <hip/hip_bf16.h>

typedef __hip_bfloat16 bf16;
typedef __attribute__((ext_vector_type(8))) short bf16x8;   // 8 bf16 (4 VGPRs)
typedef __attribute__((ext_vector_type(4))) float f32x4;    // MFMA accum

__device__ __forceinline__ float b2f(bf16 v) { return __bfloat162float(v); }
__device__ __forceinline__ bf16 f2b(float v) { return __float2bfloat16(v); }

// Scalar load/store from an external buffer whose dtype is decided by isb.
__device__ __forceinline__ float ldx(const void* p, size_t i, bool isb) {
    return isb ? b2f(((const bf16*)p)[i]) : ((const float*)p)[i];
}
__device__ __forceinline__ void stx(void* p, size_t i, bool isb, float v) {
    if (isb) ((bf16*)p)[i] = f2b(v);
    else     ((float*)p)[i] = v;
}
// Vector (8-elem) external load; i must be a multiple of 8.
__device__ __forceinline__ void ldx8(const void* p, size_t i, bool isb, float* o) {
    if (isb) {
        const bf16x8 v = *(const bf16x8*)((const bf16*)p + i);
#pragma unroll
        for (int j = 0; j < 8; j++) o[j] = b2f(((const bf16*)&v)[j]);
    } else {
        const float4 v0 = *(const float4*)((const float*)p + i);
        const float4 v1 = *(const float4*)((const float*)p + i + 4);
        o[0]=v0.x; o[1]=v0.y; o[2]=v0.z; o[3]=v0.w;
        o[4]=v1.x; o[5]=v1.y; o[6]=v1.z; o[7]=v1.w;
    }
}

// ---------------------------------------------------------------------------
// Dtype sniffer (verified round 3): decides fp32 vs bf16 external data.
// ---------------------------------------------------------------------------
__global__ void sniff_kernel(const void* __restrict__ x, int* __restrict__ flag) {
    const unsigned* w = (const unsigned*)x;
    const int t = threadIdx.x;
    int cnt = 0;
#pragma unroll
    for (int i = 0; i < 4; i++) {
        const unsigned word = w[t * 4 + i];
        const int e = (word >> 23) & 0xFF;
        cnt += (e >= 192) ? 1 : 0;
    }
    __shared__ int red[4];
#pragma unroll
    for (int o = 32; o > 0; o >>= 1) cnt += __shfl_down(cnt, o);
    if ((t & 63) == 0) red[t >> 6] = cnt;
    __syncthreads();
    if (t == 0) flag[0] = ((red[0] + red[1] + red[2] + red[3]) >= 512) ? 1 : 0;
}

// ---------------------------------------------------------------------------
// Merged weight convert+transpose for BOTH attention phases in one dispatch:
// grid (16,16,8): z 0..3 = SA {wq, wkv-lo, wkv-hi, wo} -> WT*, z 4..7 = CA
// -> WT2*. 64x64 LDS-tiled transpose, K=1024 for all.
// ---------------------------------------------------------------------------
__global__ void wconv8_kernel(const void* __restrict__ Wq,
                              const void* __restrict__ Wkv,
                              const void* __restrict__ Wo,
                              const void* __restrict__ Wq2,
                              const void* __restrict__ Wkv2,
                              const void* __restrict__ Wo2,
                              bf16* __restrict__ WTq, bf16* __restrict__ WTkv,
                              bf16* __restrict__ WTo,
                              bf16* __restrict__ WTq2, bf16* __restrict__ WTkv2,
                              bf16* __restrict__ WTo2,
                              const int* __restrict__ flagp) {
    const bool isb = (*flagp != 0);
    const int z = blockIdx.z;
    const int zz = z & 3;
    const bool ca = z >= 4;
    const void* W = ca ? ((zz == 0) ? Wq2 : (zz == 3) ? Wo2 : Wkv2)
                       : ((zz == 0) ? Wq  : (zz == 3) ? Wo  : Wkv);
    bf16* Wt      = ca ? ((zz == 0) ? WTq2 : (zz == 3) ? WTo2 : WTkv2)
                       : ((zz == 0) ? WTq  : (zz == 3) ? WTo  : WTkv);
    const int N   = (zz == 1 || zz == 2) ? 2048 : 1024;
    const int K = 1024;
    __shared__ float T[64][65];
    const int n0 = blockIdx.x * 64 + ((zz == 2) ? 1024 : 0);
    const int k0 = blockIdx.y * 64;
    const int t = threadIdx.x;
    const int rr = t >> 3, c8 = (t & 7) * 8;
#pragma unroll
    for (int i = 0; i < 2; i++) {
        const int row = rr + i * 32;
        float v[8];
        ldx8(W, (size_t)(k0 + row) * N + n0 + c8, isb, v);
#pragma unroll
        for (int j = 0; j < 8; j++) T[row][c8 + j] = v[j];
    }
    __syncthreads();
#pragma unroll
    for (int i = 0; i < 2; i++) {
        const int row = rr + i * 32;   // n-index within tile
        bf16x8 ov;
#pragma unroll
        for (int j = 0; j < 8; j++) ((bf16*)&ov)[j] = f2b(T[c8 + j][row]);
        *(bf16x8*)(Wt + (size_t)(n0 + row) * K + k0 + c8) = ov;
    }
}

// ---------------------------------------------------------------------------
// LayerNorm over F=1024, batch-fused via grid.z (per-batch strides in elems).
// ---------------------------------------------------------------------------
__global__ void ln_dual_kernel(const void* __restrict__ in, size_t in_off, long in_bs,
                               int in_ext,
                               const void* __restrict__ g1, const void* __restrict__ b1,
                               const void* __restrict__ g2, const void* __restrict__ b2,
                               bf16* __restrict__ out1, bf16* __restrict__ out2,
                               long out_bs, const int* __restrict__ flagp) {
    const int F = 1024;
    const bool isb = (*flagp != 0);
    const bool inb = in_ext ? isb : true;
    const int row = blockIdx.x;
    const int z = blockIdx.z;
    const int t = threadIdx.x;
    const size_t base = in_off + (size_t)z * in_bs + (size_t)row * F;
    const size_t obase = (size_t)z * out_bs + (size_t)row * F;

    float v[4];
    float s = 0.f;
#pragma unroll
    for (int i = 0; i < 4; i++) { v[i] = ldx(in, base + t + 256 * i, inb); s += v[i]; }

    __shared__ float red1[4];
    __shared__ float red2[4];
#pragma unroll
    for (int o = 32; o > 0; o >>= 1) s += __shfl_down(s, o);
    if ((t & 63) == 0) red1[t >> 6] = s;
    __syncthreads();
    const float mean = (red1[0] + red1[1] + red1[2] + red1[3]) * (1.0f / F);

    float ss = 0.f;
#pragma unroll
    for (int i = 0; i < 4; i++) { float d = v[i] - mean; ss += d * d; }
#pragma unroll
    for (int o = 32; o > 0; o >>= 1) ss += __shfl_down(ss, o);
    if ((t & 63) == 0) red2[t >> 6] = ss;
    __syncthreads();
    const float var = (red2[0] + red2[1] + red2[2] + red2[3]) * (1.0f / F);
    const float rn = rsqrtf(var + 1e-5f);

#pragma unroll
    for (int i = 0; i < 4; i++) {
        const int idx = t + 256 * i;
        const float nv = (v[i] - mean) * rn;
        out1[obase + idx] = f2b(nv * ldx(g1, idx, isb) + ldx(b1, idx, isb));
        if (out2) out2[obase + idx] = f2b(nv * ldx(g2, idx, isb) + ldx(b2, idx, isb));
    }
}

// ---------------------------------------------------------------------------
// Grouped GEMM args. C = A[R,1024] @ Bt^T, 128x128 tile, BK=64, 4 waves.
// ---------------------------------------------------------------------------
struct GArgs {
    const bf16* A; const bf16* Bt; void* C;
    const void* bias; const void* res;
    bf16* kb0; bf16* kb1;
    int c_ext, res_ext, N, mode, zsplit, zrows, nbx, nby;
};

// ---------------------------------------------------------------------------
// Reg-staged grouped GEMM (round-0 verified body, padded LDS). ROUND 8:
// glds variant removed (0-for-2: regressed at 1-2 blk/CU, neutral at 3.5).
// Mode-1 V-half epilogue rewritten: the old path emitted per-lane 2-BYTE
// stores at 4 KB stride (V^T is column-major vs the tile) — ~8 B dirty per
// 128 B line. New path: transpose the 128x128 V tile through LDS (reusing
// the As buffer, two 64-col passes) and emit 16 B stores, 256 B contiguous
// per V^T row. Same bytes, ~8x fewer store insts, much better line use.
// K-half and mode-0 paths byte-identical to the verified body.
// ---------------------------------------------------------------------------
__global__ __launch_bounds__(256) void gemm_fused(GArgs ga, GArgs gb, GArgs gc,
                                                  const int* __restrict__ flagp) {
    int bx = (int)blockIdx.x;
    GArgs g;
    if (bx < ga.nbx) { g = ga; }
    else if (bx < ga.nbx + gb.nbx) { g = gb; bx -= ga.nbx; }
    else { g = gc; bx -= ga.nbx + gb.nbx; }
    const int by = (int)blockIdx.y;
    if (by >= g.nby) return;               // block-uniform: no divergent barrier

    const int K = 1024;
    const bool isb = (*flagp != 0);

    __shared__ bf16 As[128][72];
    __shared__ bf16 Bs[128][72];

    const int t = threadIdx.x;
    const int w = t >> 6, lane = t & 63, li = lane & 15, quad = lane >> 4;
    const int wm = (w & 1) * 64, wn = (w >> 1) * 64;
    const int bm = by * 128, bn = bx * 128;

    f32x4 acc[4][4];
#pragma unroll
    for (int mi = 0; mi < 4; mi++)
#pragma unroll
        for (int ni = 0; ni < 4; ni++)
#pragma unroll
            for (int r = 0; r < 4; r++) acc[mi][ni][r] = 0.f;

    for (int k0 = 0; k0 < K; k0 += 64) {
#pragma unroll
        for (int c = 0; c < 4; c++) {
            const int d = c * 256 + t;
            const int row = d >> 3, ch = (d & 7) * 8;
            *(bf16x8*)&As[row][ch] = *(const bf16x8*)(g.A + (size_t)(bm + row) * K + k0 + ch);
            *(bf16x8*)&Bs[row][ch] = *(const bf16x8*)(g.Bt + (size_t)(bn + row) * K + k0 + ch);
        }
        __syncthreads();
#pragma unroll
        for (int kc = 0; kc < 2; kc++) {
            bf16x8 af[4], bfr[4];
#pragma unroll
            for (int i = 0; i < 4; i++) {
                af[i]  = *(const bf16x8*)&As[wm + i * 16 + li][kc * 32 + quad * 8];
                bfr[i] = *(const bf16x8*)&Bs[wn + i * 16 + li][kc * 32 + quad * 8];
            }
#pragma unroll
            for (int mi = 0; mi < 4; mi++)
#pragma unroll
                for (int ni = 0; ni < 4; ni++)
                    acc[mi][ni] = __builtin_amdgcn_mfma_f32_16x16x32_bf16(
                        af[mi], bfr[ni], acc[mi][ni], 0, 0, 0);
        }
        __syncthreads();
    }

    if (g.mode == 1) {
        if (bn >= 1024) {
            // -------- V block: LDS-transposed coalesced V^T store --------
            // Block rows are batch-uniform (bm..bm+127 within one batch).
            const int batch = (bm < g.zsplit) ? 0 : 1;
            bf16* kb = batch ? g.kb1 : g.kb0;
            const int brow = bm - batch * g.zsplit;
            const int vc0 = bn - 1024;
            bf16 (*T)[136] = (bf16(*)[136])&As[0][0];   // 64x136 fits in As
            const int c = t >> 2, seg = t & 3;           // c: V^T row, seg: 64B
#pragma unroll
            for (int p = 0; p < 2; p++) {
                if ((w >> 1) == p) {                     // waves owning cols p*64..
#pragma unroll
                    for (int mi = 0; mi < 4; mi++)
#pragma unroll
                        for (int ni = 0; ni < 4; ni++)
#pragma unroll
                            for (int r = 0; r < 4; r++)
                                T[ni * 16 + li][wm + mi * 16 + quad * 4 + r] =
                                    f2b(acc[mi][ni][r]);
                }
                __syncthreads();
                bf16* dst = kb + (size_t)1024 * g.zrows
                            + (size_t)(vc0 + p * 64 + c) * g.zrows + brow + seg * 32;
#pragma unroll
                for (int j = 0; j < 4; j++)
                    *(bf16x8*)(dst + j * 8) = *(const bf16x8*)&T[c][seg * 32 + j * 8];
                __syncthreads();
            }
            return;
        }
        // -------- K block: verified coalesced row-major store --------
#pragma unroll
        for (int mi = 0; mi < 4; mi++)
#pragma unroll
            for (int r = 0; r < 4; r++) {
                const int row = bm + wm + mi * 16 + quad * 4 + r;
                bf16* kb = (row < g.zsplit) ? g.kb0 : g.kb1;
                const int lrow = (row < g.zsplit) ? row : row - g.zsplit;
#pragma unroll
                for (int ni = 0; ni < 4; ni++) {
                    const int col = bn + wn + ni * 16 + li;
                    kb[(size_t)lrow * 1024 + col] = f2b(acc[mi][ni][r]);
                }
            }
        return;
    }

#pragma unroll
    for (int mi = 0; mi < 4; mi++)
#pragma unroll
        for (int r = 0; r < 4; r++) {
            const int row = bm + wm + mi * 16 + quad * 4 + r;
#pragma unroll
            for (int ni = 0; ni < 4; ni++) {
                const int col = bn + wn + ni * 16 + li;
                float v = acc[mi][ni][r];
                if (g.bias) v += ldx(g.bias, col, isb);
                if (g.res)  v += ldx(g.res, (size_t)row * g.N + col, g.res_ext ? isb : true);
                stx(g.C, (size_t)row * g.N + col, g.c_ext ? isb : true, v);
            }
        }
}

// ---------------------------------------------------------------------------
// Slow-path MFMA GEMM (round-7 verified, used only if workspace is small).
// ---------------------------------------------------------------------------
__global__ __launch_bounds__(256) void gemm_mfma(
    const bf16* __restrict__ A, long a_bs, const void* __restrict__ W,
    void* __restrict__ C, size_t c_off, long c_bs, int c_ext,
    const void* __restrict__ bias,
    const void* __restrict__ res, size_t res_off, long res_bs, int res_ext,
    int K, int N, int mode, int R,
    bf16* __restrict__ kb0, bf16* __restrict__ kb1,
    const int* __restrict__ flagp) {

    const bool isb = (*flagp != 0);
    const bool resb = res_ext ? isb : true;
    const bool cb = c_ext ? isb : true;
    const int z = blockIdx.z;

    const bf16* Az = A + (size_t)z * a_bs;
    const size_t coz = c_off + (size_t)z * c_bs;
    const size_t roz = res_off + (size_t)z * res_bs;

    __shared__ bf16 As[64][72];
    __shared__ bf16 Bs[64][72];

    const int t = threadIdx.x;
    const int w = t >> 6, lane = t & 63, li = lane & 15, quad = lane >> 4;
    const int wm = (w & 1) * 32, wn = (w >> 1) * 32;
    const int bm = blockIdx.y * 64, bn = blockIdx.x * 64;

    f32x4 acc[2][2];
#pragma unroll
    for (int mi = 0; mi < 2; mi++)
#pragma unroll
        for (int ni = 0; ni < 2; ni++)
#pragma unroll
            for (int r = 0; r < 4; r++) acc[mi][ni][r] = 0.f;

    for (int k0 = 0; k0 < K; k0 += 64) {
#pragma unroll
        for (int c = 0; c < 2; c++) {
            const int lin = t * 16 + c * 8;
            const int row = lin >> 6, kk = lin & 63;
            *(bf16x8*)&As[row][kk] = *(const bf16x8*)(Az + (size_t)(bm + row) * K + k0 + kk);
        }
#pragma unroll
        for (int c = 0; c < 2; c++) {
            const int lin = t * 16 + c * 8;
            const int kk = lin >> 6, n0 = lin & 63;
            float v[8];
            ldx8(W, (size_t)(k0 + kk) * N + bn + n0, isb, v);
            const int st = t & 7;
#pragma unroll
            for (int i = 0; i < 8; i++) {
                const int ii = (i + st) & 7;
                Bs[n0 + ii][kk] = f2b(v[ii]);
            }
        }
        __syncthreads();
#pragma unroll
        for (int kc = 0; kc < 2; kc++) {
            bf16x8 af[2], bfr[2];
#pragma unroll
            for (int mi = 0; mi < 2; mi++)
                af[mi] = *(const bf16x8*)&As[wm + mi * 16 + li][kc * 32 + quad * 8];
#pragma unroll
            for (int ni = 0; ni < 2; ni++)
                bfr[ni] = *(const bf16x8*)&Bs[wn + ni * 16 + li][kc * 32 + quad * 8];
#pragma unroll
            for (int mi = 0; mi < 2; mi++)
#pragma unroll
                for (int ni = 0; ni < 2; ni++)
                    acc[mi][ni] = __builtin_amdgcn_mfma_f32_16x16x32_bf16(
                        af[mi], bfr[ni], acc[mi][ni], 0, 0, 0);
        }
        __syncthreads();
    }

    if (mode == 1) {
        bf16* kb = z ? kb1 : kb0;
#pragma unroll
        for (int mi = 0; mi < 2; mi++)
#pragma unroll
            for (int r = 0; r < 4; r++) {
                const int row = bm + wm + mi * 16 + quad * 4 + r;
#pragma unroll
                for (int ni = 0; ni < 2; ni++) {
                    const int col = bn + wn + ni * 16 + li;
                    const float v = acc[mi][ni][r];
                    if (col < 1024)
                        kb[(size_t)row * 1024 + col] = f2b(v);
                    else
                        kb[(size_t)1024 * R + (size_t)(col - 1024) * R + row] = f2b(v);
                }
            }
        return;
    }

#pragma unroll
    for (int mi = 0; mi < 2; mi++)
#pragma unroll
        for (int r = 0; r < 4; r++) {
            const int row = bm + wm + mi * 16 + quad * 4 + r;
#pragma unroll
            for (int ni = 0; ni < 2; ni++) {
                const int col = bn + wn + ni * 16 + li;
                float v = acc[mi][ni][r];
                if (bias) v += ldx(bias, col, isb);
                if (res)  v += ldx(res, roz + (size_t)row * N + col, resb);
                stx(C, coz + (size_t)row * N + col, cb, v);
            }
        }
}

// ---------------------------------------------------------------------------
// attn_flash: round-0 verified body — best measured (134.6 µs SA). Five
// variants failed; frozen. (Codegen lottery across builds: ±5 µs.)
// ---------------------------------------------------------------------------
__global__ __launch_bounds__(64) void attn_flash(
    const bf16* __restrict__ qb, const bf16* __restrict__ kv0,
    const bf16* __restrict__ kv1,
    const void* __restrict__ rel_emb, bf16* __restrict__ out,
    long qo_bs, long out_bs, int m, int rel_off, const int* __restrict__ flagp) {

    const float SC = 0.125f * 1.44269504f;
    const bool isb = (*flagp != 0);
    const int id = blockIdx.x;
    const int xcd = id & 7;
    const int slot = id >> 3;
    const int c = (slot >> 6) * 8 + xcd;
    const int h = c & 15, z = c >> 4;
    const int q0 = (slot & 63) * 32;
    const int t = threadIdx.x;
    const int li = t & 15, quad = t >> 4;

    const bf16* qz = qb + (size_t)z * qo_bs;
    bf16* oz = out + (size_t)z * out_bs;
    const bf16* kb = z ? kv1 : kv0;
    const bf16* vtb = kb + (size_t)m * 1024;

    __shared__ float bias_s[32];
    __shared__ float tab[2080];
    __shared__ bf16 Ps[16][40];

    if (t < 32) bias_s[t] = ldx(rel_emb, t * 16 + h, isb) * SC - 40.0f;
    __syncthreads();

    const int tsz = m + 31;
    for (int i = t; i < tsz; i += 64) {
        const int rel = i - 31 - q0 + rel_off;
        const int ab = rel < 0 ? -rel : rel;
        int bucket = rel >= 0 ? 16 : 0;
        if (ab < 8) {
            bucket += ab;
        } else {
            const int p = 31 - __clz(ab);
            const int k2 = 2 * p + ((ab * ab >= (1 << (2 * p + 1))) ? 1 : 0);
            const int val = k2 + 2;
            bucket += (val > 15) ? 15 : val;
        }
        tab[i] = bias_s[bucket];
    }
    __syncthreads();

    bf16x8 aq[2][2];
#pragma unroll
    for (int g = 0; g < 2; g++)
#pragma unroll
        for (int kc = 0; kc < 2; kc++)
            aq[g][kc] = *(const bf16x8*)(qz + (size_t)(q0 + g * 16 + li) * 1024
                                         + h * 64 + kc * 32 + quad * 8);

    bf16x8 ones;
#pragma unroll
    for (int j = 0; j < 8; j++) ((short*)&ones)[j] = 0x3F80;

    f32x4 o[2][4], lac[2];
#pragma unroll
    for (int g = 0; g < 2; g++) {
#pragma unroll
        for (int r = 0; r < 4; r++) lac[g][r] = 0.f;
#pragma unroll
        for (int nb = 0; nb < 4; nb++)
#pragma unroll
            for (int r = 0; r < 4; r++) o[g][nb][r] = 0.f;
    }

    for (int j0 = 0; j0 < m; j0 += 32) {
        bf16x8 kf[4], vf[4];
#pragma unroll
        for (int nb = 0; nb < 2; nb++)
#pragma unroll
            for (int kc = 0; kc < 2; kc++)
                kf[nb * 2 + kc] = *(const bf16x8*)(
                    kb + (size_t)(j0 + nb * 16 + li) * 1024 + h * 64 + kc * 32 + quad * 8);
#pragma unroll
        for (int nb = 0; nb < 4; nb++)
            vf[nb] = *(const bf16x8*)(
                vtb + (size_t)(h * 64 + nb * 16 + li) * m + j0 + quad * 8);

#pragma unroll
        for (int g = 0; g < 2; g++) {
            f32x4 s[2];
            __builtin_amdgcn_s_setprio(1);
#pragma unroll
            for (int nb = 0; nb < 2; nb++) {
                f32x4 a;
#pragma unroll
                for (int r = 0; r < 4; r++) a[r] = 0.f;
#pragma unroll
                for (int kc = 0; kc < 2; kc++)
                    a = __builtin_amdgcn_mfma_f32_16x16x32_bf16(aq[g][kc], kf[nb * 2 + kc],
                                                                a, 0, 0, 0);
                s[nb] = a;
            }
            __builtin_amdgcn_s_setprio(0);
#pragma unroll
            for (int nb = 0; nb < 2; nb++)
#pragma unroll
                for (int r = 0; r < 4; r++) {
                    const int ti = j0 + nb * 16 + li + 31 - (g * 16 + quad * 4 + r);
                    s[nb][r] = exp2f(fmaf(s[nb][r], SC, tab[ti]));
                }
#pragma unroll
            for (int nb = 0; nb < 2; nb++)
#pragma unroll
                for (int r = 0; r < 4; r++)
                    Ps[quad * 4 + r][nb * 16 + li] = f2b(s[nb][r]);
            const bf16x8 ap = *(const bf16x8*)&Ps[li][quad * 8];
            __builtin_amdgcn_s_setprio(1);
#pragma unroll
            for (int nb = 0; nb < 4; nb++)
                o[g][nb] = __builtin_amdgcn_mfma_f32_16x16x32_bf16(ap, vf[nb],
                                                                   o[g][nb], 0, 0, 0);
            lac[g] = __builtin_amdgcn_mfma_f32_16x16x32_bf16(ap, ones, lac[g], 0, 0, 0);
            __builtin_amdgcn_s_setprio(0);
        }
    }

#pragma unroll
    for (int g = 0; g < 2; g++)
#pragma unroll
        for (int r = 0; r < 4; r++) {
            const float inv = 1.0f / lac[g][r];
            const int qi = q0 + g * 16 + quad * 4 + r;
#pragma unroll
            for (int nb = 0; nb < 4; nb++)
                oz[(size_t)qi * 1024 + h * 64 + nb * 16 + li] = f2b(o[g][nb][r] * inv);
        }
}

// ---------------------------------------------------------------------------
// Launcher. Fast path (ws >= 56 MB + 256; measured ws = 256 MB):
//   F_A|F_B|F_C (24 MB) + WT (8) + F_X (8) + F_Y (6) + WT2 (8) = 54 MB.
// Round-5 schedule (best: 489 µs) with the V^T-transposed kv epilogue.
// Fallback: round-7 plan (24 MB).
// ---------------------------------------------------------------------------
extern "C" void kernel_launch(void* const* d_in, const int* in_sizes, int n_in,
                              void* d_out, int out_size, void* d_ws, size_t ws_size,
                              hipStream_t stream) {
    const long M1 = 1024 * 1024;
    const long M2 = 2 * 1024 * 1024;
    const long M4 = 4 * 1024 * 1024;
    if (ws_size < 24u * 1024 * 1024 + 256) return;

    const void* x      = d_in[0];
    const void* ctx    = d_in[1];
    const void* sa_ng  = d_in[2];
    const void* sa_nb  = d_in[3];
    const void* sa_ncg = d_in[4];
    const void* sa_ncb = d_in[5];
    const void* sa_wq  = d_in[6];
    const void* sa_wkv = d_in[7];
    const void* sa_wo  = d_in[8];
    const void* sa_bo  = d_in[9];
    const void* sa_rel = d_in[10];
    const void* ca_ng  = d_in[11];
    const void* ca_nb  = d_in[12];
    const void* ca_ncg = d_in[13];
    const void* ca_ncb = d_in[14];
    const void* ca_wq  = d_in[15];
    const void* ca_wkv = d_in[16];
    const void* ca_wo  = d_in[17];
    const void* ca_bo  = d_in[18];
    const void* ca_rel = d_in[19];

    int* flag = (int*)d_ws;
    bf16* F_A = (bf16*)((char*)d_ws + 256);
    bf16* F_B = F_A + M4;
    bf16* F_C = F_B + M4;
    bf16* WT  = F_C + M4;                // fast path only (SA weights)
    bf16* F_X = WT + M4;                 // fast path only (xn buffer)
    bf16* F_Y = F_X + M4;                // fast path only (ctx-LN + CA K/V)
    bf16* WT2 = F_Y + 3 * M1;            // fast path only (CA weights)
    bf16* qd  = (bf16*)d_out;            // d_out as bf16 scratch (q / ao)

    sniff_kernel<<<1, 256, 0, stream>>>(x, flag);

    if (ws_size >= 56u * 1024 * 1024 + 256) {
        bf16* WTq  = WT;                 // [1024][1024]
        bf16* WTkv = WT + M1;            // [2048][1024]
        bf16* WTo  = WT + 3 * M1;        // [1024][1024]
        bf16* WT2q  = WT2;
        bf16* WT2kv = WT2 + M1;
        bf16* WT2o  = WT2 + 3 * M1;
        bf16* CAK0 = F_Y + M1;           // z0: K[512][1024] + V^T[1024][512]
        bf16* CAK1 = F_Y + 2 * M1;       // z1: same layout
        GArgs gz = {};                   // empty slot (nbx = 0)

        // ===== prologue: all weight transposes + both input LNs =====
        wconv8_kernel<<<dim3(16, 16, 8), 256, 0, stream>>>(
            sa_wq, sa_wkv, sa_wo, ca_wq, ca_wkv, ca_wo,
            WTq, WTkv, WTo, WT2q, WT2kv, WT2o, flag);
        ln_dual_kernel<<<dim3(2048, 1, 2), 256, 0, stream>>>(
            x, 0, M2, 1, sa_ng, sa_nb, sa_ncg, sa_ncb, F_X, F_B, M2, flag);
        ln_dual_kernel<<<dim3(512, 1, 2), 256, 0, stream>>>(
            ctx, 0, 512 * 1024, 1, ca_ncg, ca_ncb, nullptr, nullptr,
            F_Y, nullptr, 512 * 1024, flag);

        // ===== BIG: SA-q + SA-kv + CA-kv (all independent) =====
        {
            GArgs gq = {};
            gq.A = F_X; gq.Bt = WTq; gq.C = qd;
            gq.N = 1024; gq.nbx = 8; gq.nby = 32;
            GArgs gkv = {};
            gkv.A = F_B; gkv.Bt = WTkv;
            gkv.N = 2048; gkv.mode = 1; gkv.zsplit = 2048; gkv.zrows = 2048;
            gkv.kb0 = F_A; gkv.kb1 = F_C; gkv.nbx = 16; gkv.nby = 32;
            GArgs gca = {};
            gca.A = F_Y; gca.Bt = WT2kv;
            gca.N = 2048; gca.mode = 1; gca.zsplit = 512; gca.zrows = 512;
            gca.kb0 = CAK0; gca.kb1 = CAK1; gca.nbx = 16; gca.nby = 8;
            gemm_fused<<<dim3(40, 32), 256, 0, stream>>>(gq, gkv, gca, flag);
        }

        // ===== self-attention + o-proj =====
        attn_flash<<<dim3(2048), 64, 0, stream>>>(
            qd, F_A, F_C, sa_rel, qd, M2, M2, 2048, 0, flag);
        {
            GArgs go = {};
            go.A = qd; go.Bt = WTo; go.C = F_B;
            go.bias = sa_bo; go.res = x; go.res_ext = 1;
            go.N = 1024; go.nbx = 8; go.nby = 32;
            gemm_fused<<<dim3(8, 32), 256, 0, stream>>>(go, gz, gz, flag);
        }

        // ===== cross-attention =====
        ln_dual_kernel<<<dim3(2048, 1, 2), 256, 0, stream>>>(
            F_B, 0, M2, 0, ca_ng, ca_nb, nullptr, nullptr, F_X, nullptr, M2, flag);
        {
            GArgs gq = {};
            gq.A = F_X; gq.Bt = WT2q; gq.C = qd;
            gq.N = 1024; gq.nbx = 8; gq.nby = 32;
            gemm_fused<<<dim3(8, 32), 256, 0, stream>>>(gq, gz, gz, flag);
        }
        attn_flash<<<dim3(2048), 64, 0, stream>>>(
            qd, CAK0, CAK1, ca_rel, F_C, M2, M2, 512, 1536, flag);
        {
            GArgs go = {};
            go.A = F_C; go.Bt = WT2o; go.C = d_out; go.c_ext = 1;
            go.bias = ca_bo; go.res = F_B;
            go.N = 1024; go.nbx = 8; go.nby = 32;
            gemm_fused<<<dim3(8, 32), 256, 0, stream>>>(go, gz, gz, flag);
        }
        return;
    }

    // ================= fallback: round-7 verified plan =================
    ln_dual_kernel<<<dim3(2048, 1, 2), 256, 0, stream>>>(
        x, 0, M2, 1, sa_ng, sa_nb, sa_ncg, sa_ncb, F_A, F_B, M2, flag);
    gemm_mfma<<<dim3(16, 32, 2), 256, 0, stream>>>(
        F_A, M2, sa_wq, qd, 0, M2, 0, nullptr, nullptr, 0, 0, 0,
        1024, 1024, 0, 0, nullptr, nullptr, flag);
    gemm_mfma<<<dim3(32, 32, 2), 256, 0, stream>>>(
        F_B, M2, sa_wkv, nullptr, 0, 0, 0, nullptr, nullptr, 0, 0, 0,
        1024, 2048, 1, 2048, F_A, F_C, flag);
    attn_flash<<<dim3(2048), 64, 0, stream>>>(
        qd, F_A, F_C, sa_rel, qd, M2, M2, 2048, 0, flag);
    gemm_mfma<<<dim3(16, 32, 2), 256, 0, stream>>>(
        qd, M2, sa_wo, F_B, 0, M2, 0, sa_bo, x, 0, M2, 1,
        1024, 1024, 0, 0, nullptr, nullptr, flag);

    ln_dual_kernel<<<dim3(2048, 1, 2), 256, 0, stream>>>(
        F_B, 0, M2, 0, ca_ng, ca_nb, nullptr, nullptr, F_A, nullptr, M2, flag);
    ln_dual_kernel<<<dim3(512, 1, 2), 256, 0, stream>>>(
        ctx, 0, 512 * 1024, 1, ca_ncg, ca_ncb, nullptr, nullptr,
        F_C, nullptr, 512 * 1024, flag);
    gemm_mfma<<<dim3(16, 32, 2), 256, 0, stream>>>(
        F_A, M2, ca_wq, qd, 0, M2, 0, nullptr, nullptr, 0, 0, 0,
        1024, 1024, 0, 0, nullptr, nullptr, flag);
    gemm_mfma<<<dim3(32, 8, 2), 256, 0, stream>>>(
        F_C, 512 * 1024, ca_wkv, nullptr, 0, 0, 0, nullptr, nullptr, 0, 0, 0,
        1024, 2048, 1, 512, F_A, F_A + M1, flag);
    attn_flash<<<dim3(2048), 64, 0, stream>>>(
        qd, F_A, F_A + M1, ca_rel, F_C, M2, M2, 512, 1536, flag);
    gemm_mfma<<<dim3(16, 32, 2), 256, 0, stream>>>(
        F_C, M2, ca_wo, d_out, 0, M2, 1, ca_bo, F_B, 0, M2, 0,
        1024, 1024, 0, 0, nullptr, nullptr, flag);
}

// Round 10
// 460.287 us; speedup vs baseline: 1.1691x; 1.0469x over previous
//
#include <hip/hip_runtime.h>
#include <hip/hip_bf16.h>

typedef __hip_bfloat16 bf16;
typedef __attribute__((ext_vector_type(8))) short bf16x8;   // 8 bf16 (4 VGPRs)
typedef __attribute__((ext_vector_type(4))) float f32x4;    // MFMA accum

__device__ __forceinline__ float b2f(bf16 v) { return __bfloat162float(v); }
__device__ __forceinline__ bf16 f2b(float v) { return __float2bfloat16(v); }

// Scalar load/store from an external buffer whose dtype is decided by isb.
__device__ __forceinline__ float ldx(const void* p, size_t i, bool isb) {
    return isb ? b2f(((const bf16*)p)[i]) : ((const float*)p)[i];
}
__device__ __forceinline__ void stx(void* p, size_t i, bool isb, float v) {
    if (isb) ((bf16*)p)[i] = f2b(v);
    else     ((float*)p)[i] = v;
}
// Vector (8-elem) external load; i must be a multiple of 8.
__device__ __forceinline__ void ldx8(const void* p, size_t i, bool isb, float* o) {
    if (isb) {
        const bf16x8 v = *(const bf16x8*)((const bf16*)p + i);
#pragma unroll
        for (int j = 0; j < 8; j++) o[j] = b2f(((const bf16*)&v)[j]);
    } else {
        const float4 v0 = *(const float4*)((const float*)p + i);
        const float4 v1 = *(const float4*)((const float*)p + i + 4);
        o[0]=v0.x; o[1]=v0.y; o[2]=v0.z; o[3]=v0.w;
        o[4]=v1.x; o[5]=v1.y; o[6]=v1.z; o[7]=v1.w;
    }
}

// ---------------------------------------------------------------------------
// Dtype sniffer (verified round 3): decides fp32 vs bf16 external data.
// ---------------------------------------------------------------------------
__global__ void sniff_kernel(const void* __restrict__ x, int* __restrict__ flag) {
    const unsigned* w = (const unsigned*)x;
    const int t = threadIdx.x;
    int cnt = 0;
#pragma unroll
    for (int i = 0; i < 4; i++) {
        const unsigned word = w[t * 4 + i];
        const int e = (word >> 23) & 0xFF;
        cnt += (e >= 192) ? 1 : 0;
    }
    __shared__ int red[4];
#pragma unroll
    for (int o = 32; o > 0; o >>= 1) cnt += __shfl_down(cnt, o);
    if ((t & 63) == 0) red[t >> 6] = cnt;
    __syncthreads();
    if (t == 0) flag[0] = ((red[0] + red[1] + red[2] + red[3]) >= 512) ? 1 : 0;
}

// ---------------------------------------------------------------------------
// Merged weight convert+transpose for BOTH attention phases in one dispatch:
// grid (16,16,8): z 0..3 = SA {wq, wkv-lo, wkv-hi, wo} -> WT*, z 4..7 = CA
// -> WT2*. 64x64 LDS-tiled transpose, K=1024 for all.
// ---------------------------------------------------------------------------
__global__ void wconv8_kernel(const void* __restrict__ Wq,
                              const void* __restrict__ Wkv,
                              const void* __restrict__ Wo,
                              const void* __restrict__ Wq2,
                              const void* __restrict__ Wkv2,
                              const void* __restrict__ Wo2,
                              bf16* __restrict__ WTq, bf16* __restrict__ WTkv,
                              bf16* __restrict__ WTo,
                              bf16* __restrict__ WTq2, bf16* __restrict__ WTkv2,
                              bf16* __restrict__ WTo2,
                              const int* __restrict__ flagp) {
    const bool isb = (*flagp != 0);
    const int z = blockIdx.z;
    const int zz = z & 3;
    const bool ca = z >= 4;
    const void* W = ca ? ((zz == 0) ? Wq2 : (zz == 3) ? Wo2 : Wkv2)
                       : ((zz == 0) ? Wq  : (zz == 3) ? Wo  : Wkv);
    bf16* Wt      = ca ? ((zz == 0) ? WTq2 : (zz == 3) ? WTo2 : WTkv2)
                       : ((zz == 0) ? WTq  : (zz == 3) ? WTo  : WTkv);
    const int N   = (zz == 1 || zz == 2) ? 2048 : 1024;
    const int K = 1024;
    __shared__ float T[64][65];
    const int n0 = blockIdx.x * 64 + ((zz == 2) ? 1024 : 0);
    const int k0 = blockIdx.y * 64;
    const int t = threadIdx.x;
    const int rr = t >> 3, c8 = (t & 7) * 8;
#pragma unroll
    for (int i = 0; i < 2; i++) {
        const int row = rr + i * 32;
        float v[8];
        ldx8(W, (size_t)(k0 + row) * N + n0 + c8, isb, v);
#pragma unroll
        for (int j = 0; j < 8; j++) T[row][c8 + j] = v[j];
    }
    __syncthreads();
#pragma unroll
    for (int i = 0; i < 2; i++) {
        const int row = rr + i * 32;   // n-index within tile
        bf16x8 ov;
#pragma unroll
        for (int j = 0; j < 8; j++) ((bf16*)&ov)[j] = f2b(T[c8 + j][row]);
        *(bf16x8*)(Wt + (size_t)(n0 + row) * K + k0 + c8) = ov;
    }
}

// ---------------------------------------------------------------------------
// LayerNorm over F=1024, batch-fused via grid.z (per-batch strides in elems).
// ---------------------------------------------------------------------------
__global__ void ln_dual_kernel(const void* __restrict__ in, size_t in_off, long in_bs,
                               int in_ext,
                               const void* __restrict__ g1, const void* __restrict__ b1,
                               const void* __restrict__ g2, const void* __restrict__ b2,
                               bf16* __restrict__ out1, bf16* __restrict__ out2,
                               long out_bs, const int* __restrict__ flagp) {
    const int F = 1024;
    const bool isb = (*flagp != 0);
    const bool inb = in_ext ? isb : true;
    const int row = blockIdx.x;
    const int z = blockIdx.z;
    const int t = threadIdx.x;
    const size_t base = in_off + (size_t)z * in_bs + (size_t)row * F;
    const size_t obase = (size_t)z * out_bs + (size_t)row * F;

    float v[4];
    float s = 0.f;
#pragma unroll
    for (int i = 0; i < 4; i++) { v[i] = ldx(in, base + t + 256 * i, inb); s += v[i]; }

    __shared__ float red1[4];
    __shared__ float red2[4];
#pragma unroll
    for (int o = 32; o > 0; o >>= 1) s += __shfl_down(s, o);
    if ((t & 63) == 0) red1[t >> 6] = s;
    __syncthreads();
    const float mean = (red1[0] + red1[1] + red1[2] + red1[3]) * (1.0f / F);

    float ss = 0.f;
#pragma unroll
    for (int i = 0; i < 4; i++) { float d = v[i] - mean; ss += d * d; }
#pragma unroll
    for (int o = 32; o > 0; o >>= 1) ss += __shfl_down(ss, o);
    if ((t & 63) == 0) red2[t >> 6] = ss;
    __syncthreads();
    const float var = (red2[0] + red2[1] + red2[2] + red2[3]) * (1.0f / F);
    const float rn = rsqrtf(var + 1e-5f);

#pragma unroll
    for (int i = 0; i < 4; i++) {
        const int idx = t + 256 * i;
        const float nv = (v[i] - mean) * rn;
        out1[obase + idx] = f2b(nv * ldx(g1, idx, isb) + ldx(b1, idx, isb));
        if (out2) out2[obase + idx] = f2b(nv * ldx(g2, idx, isb) + ldx(b2, idx, isb));
    }
}

// ---------------------------------------------------------------------------
// Grouped GEMM args. C = A[R,1024] @ Bt^T, 128x128 tile, BK=64, 4 waves.
// ---------------------------------------------------------------------------
struct GArgs {
    const bf16* A; const bf16* Bt; void* C;
    const void* bias; const void* res;
    bf16* kb0; bf16* kb1;
    int c_ext, res_ext, N, mode, zsplit, zrows, nbx, nby;
};

// ---------------------------------------------------------------------------
// Reg-staged grouped GEMM (verified body, padded LDS). Mode-1 V-half writes
// V^T via LDS transpose (round-8 win: 16B contiguous stores). Used for the
// BIG 3-slot dispatch (3.5 blocks/CU).
// ---------------------------------------------------------------------------
__global__ __launch_bounds__(256) void gemm_fused(GArgs ga, GArgs gb, GArgs gc,
                                                  const int* __restrict__ flagp) {
    int bx = (int)blockIdx.x;
    GArgs g;
    if (bx < ga.nbx) { g = ga; }
    else if (bx < ga.nbx + gb.nbx) { g = gb; bx -= ga.nbx; }
    else { g = gc; bx -= ga.nbx + gb.nbx; }
    const int by = (int)blockIdx.y;
    if (by >= g.nby) return;               // block-uniform: no divergent barrier

    const int K = 1024;
    const bool isb = (*flagp != 0);

    __shared__ bf16 As[128][72];
    __shared__ bf16 Bs[128][72];

    const int t = threadIdx.x;
    const int w = t >> 6, lane = t & 63, li = lane & 15, quad = lane >> 4;
    const int wm = (w & 1) * 64, wn = (w >> 1) * 64;
    const int bm = by * 128, bn = bx * 128;

    f32x4 acc[4][4];
#pragma unroll
    for (int mi = 0; mi < 4; mi++)
#pragma unroll
        for (int ni = 0; ni < 4; ni++)
#pragma unroll
            for (int r = 0; r < 4; r++) acc[mi][ni][r] = 0.f;

    for (int k0 = 0; k0 < K; k0 += 64) {
#pragma unroll
        for (int c = 0; c < 4; c++) {
            const int d = c * 256 + t;
            const int row = d >> 3, ch = (d & 7) * 8;
            *(bf16x8*)&As[row][ch] = *(const bf16x8*)(g.A + (size_t)(bm + row) * K + k0 + ch);
            *(bf16x8*)&Bs[row][ch] = *(const bf16x8*)(g.Bt + (size_t)(bn + row) * K + k0 + ch);
        }
        __syncthreads();
#pragma unroll
        for (int kc = 0; kc < 2; kc++) {
            bf16x8 af[4], bfr[4];
#pragma unroll
            for (int i = 0; i < 4; i++) {
                af[i]  = *(const bf16x8*)&As[wm + i * 16 + li][kc * 32 + quad * 8];
                bfr[i] = *(const bf16x8*)&Bs[wn + i * 16 + li][kc * 32 + quad * 8];
            }
#pragma unroll
            for (int mi = 0; mi < 4; mi++)
#pragma unroll
                for (int ni = 0; ni < 4; ni++)
                    acc[mi][ni] = __builtin_amdgcn_mfma_f32_16x16x32_bf16(
                        af[mi], bfr[ni], acc[mi][ni], 0, 0, 0);
        }
        __syncthreads();
    }

    if (g.mode == 1) {
        if (bn >= 1024) {
            // -------- V block: LDS-transposed coalesced V^T store --------
            const int batch = (bm < g.zsplit) ? 0 : 1;
            bf16* kb = batch ? g.kb1 : g.kb0;
            const int brow = bm - batch * g.zsplit;
            const int vc0 = bn - 1024;
            bf16 (*T)[136] = (bf16(*)[136])&As[0][0];   // 64x136 fits in As
            const int c = t >> 2, seg = t & 3;           // c: V^T row, seg: 64B
#pragma unroll
            for (int p = 0; p < 2; p++) {
                if ((w >> 1) == p) {                     // waves owning cols p*64..
#pragma unroll
                    for (int mi = 0; mi < 4; mi++)
#pragma unroll
                        for (int ni = 0; ni < 4; ni++)
#pragma unroll
                            for (int r = 0; r < 4; r++)
                                T[ni * 16 + li][wm + mi * 16 + quad * 4 + r] =
                                    f2b(acc[mi][ni][r]);
                }
                __syncthreads();
                bf16* dst = kb + (size_t)1024 * g.zrows
                            + (size_t)(vc0 + p * 64 + c) * g.zrows + brow + seg * 32;
#pragma unroll
                for (int j = 0; j < 4; j++)
                    *(bf16x8*)(dst + j * 8) = *(const bf16x8*)&T[c][seg * 32 + j * 8];
                __syncthreads();
            }
            return;
        }
        // -------- K block: verified coalesced row-major store --------
#pragma unroll
        for (int mi = 0; mi < 4; mi++)
#pragma unroll
            for (int r = 0; r < 4; r++) {
                const int row = bm + wm + mi * 16 + quad * 4 + r;
                bf16* kb = (row < g.zsplit) ? g.kb0 : g.kb1;
                const int lrow = (row < g.zsplit) ? row : row - g.zsplit;
#pragma unroll
                for (int ni = 0; ni < 4; ni++) {
                    const int col = bn + wn + ni * 16 + li;
                    kb[(size_t)lrow * 1024 + col] = f2b(acc[mi][ni][r]);
                }
            }
        return;
    }

#pragma unroll
    for (int mi = 0; mi < 4; mi++)
#pragma unroll
        for (int r = 0; r < 4; r++) {
            const int row = bm + wm + mi * 16 + quad * 4 + r;
#pragma unroll
            for (int ni = 0; ni < 4; ni++) {
                const int col = bn + wn + ni * 16 + li;
                float v = acc[mi][ni][r];
                if (g.bias) v += ldx(g.bias, col, isb);
                if (g.res)  v += ldx(g.res, (size_t)row * g.N + col, g.res_ext ? isb : true);
                stx(g.C, (size_t)row * g.N + col, g.c_ext ? isb : true, v);
            }
        }
}

// ---------------------------------------------------------------------------
// ROUND 9 (retry; round-9 bench was an infra failure): 64x64-tile mode-0
// GEMM for the three standalone 256-block GEMMs (SA-oproj, CA-q, CA-oproj).
// At 128x128 tiles these run 256 blocks = 1 block/CU — zero inter-block
// overlap (the only latency-hiding mechanism at these grids, m114; raising
// blocks/CU paid in rounds 4/5). 64x64 tile -> grid (16,64) = 1024 blocks
// = 4 blocks/CU. MFMA core = byte-identical fragment pattern of verified
// gemm_mfma; staging = gemm_fused's Bt-layout vector path.
// ---------------------------------------------------------------------------
__global__ __launch_bounds__(256) void gemm_t64(
    const bf16* __restrict__ A, const bf16* __restrict__ Bt,
    void* __restrict__ C, int c_ext,
    const void* __restrict__ bias,
    const void* __restrict__ res, int res_ext, int N,
    const int* __restrict__ flagp) {

    const int K = 1024;
    const bool isb = (*flagp != 0);

    __shared__ bf16 As[64][72];
    __shared__ bf16 Bs[64][72];

    const int t = threadIdx.x;
    const int w = t >> 6, lane = t & 63, li = lane & 15, quad = lane >> 4;
    const int wm = (w & 1) * 32, wn = (w >> 1) * 32;
    const int bm = blockIdx.y * 64, bn = blockIdx.x * 64;

    f32x4 acc[2][2];
#pragma unroll
    for (int mi = 0; mi < 2; mi++)
#pragma unroll
        for (int ni = 0; ni < 2; ni++)
#pragma unroll
            for (int r = 0; r < 4; r++) acc[mi][ni][r] = 0.f;

    for (int k0 = 0; k0 < K; k0 += 64) {
#pragma unroll
        for (int c = 0; c < 2; c++) {
            const int d = c * 256 + t;
            const int row = d >> 3, ch = (d & 7) * 8;
            *(bf16x8*)&As[row][ch] = *(const bf16x8*)(A + (size_t)(bm + row) * K + k0 + ch);
            *(bf16x8*)&Bs[row][ch] = *(const bf16x8*)(Bt + (size_t)(bn + row) * K + k0 + ch);
        }
        __syncthreads();
#pragma unroll
        for (int kc = 0; kc < 2; kc++) {
            bf16x8 af[2], bfr[2];
#pragma unroll
            for (int mi = 0; mi < 2; mi++)
                af[mi] = *(const bf16x8*)&As[wm + mi * 16 + li][kc * 32 + quad * 8];
#pragma unroll
            for (int ni = 0; ni < 2; ni++)
                bfr[ni] = *(const bf16x8*)&Bs[wn + ni * 16 + li][kc * 32 + quad * 8];
#pragma unroll
            for (int mi = 0; mi < 2; mi++)
#pragma unroll
                for (int ni = 0; ni < 2; ni++)
                    acc[mi][ni] = __builtin_amdgcn_mfma_f32_16x16x32_bf16(
                        af[mi], bfr[ni], acc[mi][ni], 0, 0, 0);
        }
        __syncthreads();
    }

#pragma unroll
    for (int mi = 0; mi < 2; mi++)
#pragma unroll
        for (int r = 0; r < 4; r++) {
            const int row = bm + wm + mi * 16 + quad * 4 + r;
#pragma unroll
            for (int ni = 0; ni < 2; ni++) {
                const int col = bn + wn + ni * 16 + li;
                float v = acc[mi][ni][r];
                if (bias) v += ldx(bias, col, isb);
                if (res)  v += ldx(res, (size_t)row * N + col, res_ext ? isb : true);
                stx(C, (size_t)row * N + col, c_ext ? isb : true, v);
            }
        }
}

// ---------------------------------------------------------------------------
// Slow-path MFMA GEMM (round-7 verified, used only if workspace is small).
// ---------------------------------------------------------------------------
__global__ __launch_bounds__(256) void gemm_mfma(
    const bf16* __restrict__ A, long a_bs, const void* __restrict__ W,
    void* __restrict__ C, size_t c_off, long c_bs, int c_ext,
    const void* __restrict__ bias,
    const void* __restrict__ res, size_t res_off, long res_bs, int res_ext,
    int K, int N, int mode, int R,
    bf16* __restrict__ kb0, bf16* __restrict__ kb1,
    const int* __restrict__ flagp) {

    const bool isb = (*flagp != 0);
    const bool resb = res_ext ? isb : true;
    const bool cb = c_ext ? isb : true;
    const int z = blockIdx.z;

    const bf16* Az = A + (size_t)z * a_bs;
    const size_t coz = c_off + (size_t)z * c_bs;
    const size_t roz = res_off + (size_t)z * res_bs;

    __shared__ bf16 As[64][72];
    __shared__ bf16 Bs[64][72];

    const int t = threadIdx.x;
    const int w = t >> 6, lane = t & 63, li = lane & 15, quad = lane >> 4;
    const int wm = (w & 1) * 32, wn = (w >> 1) * 32;
    const int bm = blockIdx.y * 64, bn = blockIdx.x * 64;

    f32x4 acc[2][2];
#pragma unroll
    for (int mi = 0; mi < 2; mi++)
#pragma unroll
        for (int ni = 0; ni < 2; ni++)
#pragma unroll
            for (int r = 0; r < 4; r++) acc[mi][ni][r] = 0.f;

    for (int k0 = 0; k0 < K; k0 += 64) {
#pragma unroll
        for (int c = 0; c < 2; c++) {
            const int lin = t * 16 + c * 8;
            const int row = lin >> 6, kk = lin & 63;
            *(bf16x8*)&As[row][kk] = *(const bf16x8*)(Az + (size_t)(bm + row) * K + k0 + kk);
        }
#pragma unroll
        for (int c = 0; c < 2; c++) {
            const int lin = t * 16 + c * 8;
            const int kk = lin >> 6, n0 = lin & 63;
            float v[8];
            ldx8(W, (size_t)(k0 + kk) * N + bn + n0, isb, v);
            const int st = t & 7;
#pragma unroll
            for (int i = 0; i < 8; i++) {
                const int ii = (i + st) & 7;
                Bs[n0 + ii][kk] = f2b(v[ii]);
            }
        }
        __syncthreads();
#pragma unroll
        for (int kc = 0; kc < 2; kc++) {
            bf16x8 af[2], bfr[2];
#pragma unroll
            for (int mi = 0; mi < 2; mi++)
                af[mi] = *(const bf16x8*)&As[wm + mi * 16 + li][kc * 32 + quad * 8];
#pragma unroll
            for (int ni = 0; ni < 2; ni++)
                bfr[ni] = *(const bf16x8*)&Bs[wn + ni * 16 + li][kc * 32 + quad * 8];
#pragma unroll
            for (int mi = 0; mi < 2; mi++)
#pragma unroll
                for (int ni = 0; ni < 2; ni++)
                    acc[mi][ni] = __builtin_amdgcn_mfma_f32_16x16x32_bf16(
                        af[mi], bfr[ni], acc[mi][ni], 0, 0, 0);
        }
        __syncthreads();
    }

    if (mode == 1) {
        bf16* kb = z ? kb1 : kb0;
#pragma unroll
        for (int mi = 0; mi < 2; mi++)
#pragma unroll
            for (int r = 0; r < 4; r++) {
                const int row = bm + wm + mi * 16 + quad * 4 + r;
#pragma unroll
                for (int ni = 0; ni < 2; ni++) {
                    const int col = bn + wn + ni * 16 + li;
                    const float v = acc[mi][ni][r];
                    if (col < 1024)
                        kb[(size_t)row * 1024 + col] = f2b(v);
                    else
                        kb[(size_t)1024 * R + (size_t)(col - 1024) * R + row] = f2b(v);
                }
            }
        return;
    }

#pragma unroll
    for (int mi = 0; mi < 2; mi++)
#pragma unroll
        for (int r = 0; r < 4; r++) {
            const int row = bm + wm + mi * 16 + quad * 4 + r;
#pragma unroll
            for (int ni = 0; ni < 2; ni++) {
                const int col = bn + wn + ni * 16 + li;
                float v = acc[mi][ni][r];
                if (bias) v += ldx(bias, col, isb);
                if (res)  v += ldx(res, roz + (size_t)row * N + col, resb);
                stx(C, coz + (size_t)row * N + col, cb, v);
            }
        }
}

// ---------------------------------------------------------------------------
// attn_flash: round-0 verified body — best measured (134.6 µs SA). Five
// variants failed; frozen. (Codegen lottery across builds: ±5 µs.)
// ---------------------------------------------------------------------------
__global__ __launch_bounds__(64) void attn_flash(
    const bf16* __restrict__ qb, const bf16* __restrict__ kv0,
    const bf16* __restrict__ kv1,
    const void* __restrict__ rel_emb, bf16* __restrict__ out,
    long qo_bs, long out_bs, int m, int rel_off, const int* __restrict__ flagp) {

    const float SC = 0.125f * 1.44269504f;
    const bool isb = (*flagp != 0);
    const int id = blockIdx.x;
    const int xcd = id & 7;
    const int slot = id >> 3;
    const int c = (slot >> 6) * 8 + xcd;
    const int h = c & 15, z = c >> 4;
    const int q0 = (slot & 63) * 32;
    const int t = threadIdx.x;
    const int li = t & 15, quad = t >> 4;

    const bf16* qz = qb + (size_t)z * qo_bs;
    bf16* oz = out + (size_t)z * out_bs;
    const bf16* kb = z ? kv1 : kv0;
    const bf16* vtb = kb + (size_t)m * 1024;

    __shared__ float bias_s[32];
    __shared__ float tab[2080];
    __shared__ bf16 Ps[16][40];

    if (t < 32) bias_s[t] = ldx(rel_emb, t * 16 + h, isb) * SC - 40.0f;
    __syncthreads();

    const int tsz = m + 31;
    for (int i = t; i < tsz; i += 64) {
        const int rel = i - 31 - q0 + rel_off;
        const int ab = rel < 0 ? -rel : rel;
        int bucket = rel >= 0 ? 16 : 0;
        if (ab < 8) {
            bucket += ab;
        } else {
            const int p = 31 - __clz(ab);
            const int k2 = 2 * p + ((ab * ab >= (1 << (2 * p + 1))) ? 1 : 0);
            const int val = k2 + 2;
            bucket += (val > 15) ? 15 : val;
        }
        tab[i] = bias_s[bucket];
    }
    __syncthreads();

    bf16x8 aq[2][2];
#pragma unroll
    for (int g = 0; g < 2; g++)
#pragma unroll
        for (int kc = 0; kc < 2; kc++)
            aq[g][kc] = *(const bf16x8*)(qz + (size_t)(q0 + g * 16 + li) * 1024
                                         + h * 64 + kc * 32 + quad * 8);

    bf16x8 ones;
#pragma unroll
    for (int j = 0; j < 8; j++) ((short*)&ones)[j] = 0x3F80;

    f32x4 o[2][4], lac[2];
#pragma unroll
    for (int g = 0; g < 2; g++) {
#pragma unroll
        for (int r = 0; r < 4; r++) lac[g][r] = 0.f;
#pragma unroll
        for (int nb = 0; nb < 4; nb++)
#pragma unroll
            for (int r = 0; r < 4; r++) o[g][nb][r] = 0.f;
    }

    for (int j0 = 0; j0 < m; j0 += 32) {
        bf16x8 kf[4], vf[4];
#pragma unroll
        for (int nb = 0; nb < 2; nb++)
#pragma unroll
            for (int kc = 0; kc < 2; kc++)
                kf[nb * 2 + kc] = *(const bf16x8*)(
                    kb + (size_t)(j0 + nb * 16 + li) * 1024 + h * 64 + kc * 32 + quad * 8);
#pragma unroll
        for (int nb = 0; nb < 4; nb++)
            vf[nb] = *(const bf16x8*)(
                vtb + (size_t)(h * 64 + nb * 16 + li) * m + j0 + quad * 8);

#pragma unroll
        for (int g = 0; g < 2; g++) {
            f32x4 s[2];
            __builtin_amdgcn_s_setprio(1);
#pragma unroll
            for (int nb = 0; nb < 2; nb++) {
                f32x4 a;
#pragma unroll
                for (int r = 0; r < 4; r++) a[r] = 0.f;
#pragma unroll
                for (int kc = 0; kc < 2; kc++)
                    a = __builtin_amdgcn_mfma_f32_16x16x32_bf16(aq[g][kc], kf[nb * 2 + kc],
                                                                a, 0, 0, 0);
                s[nb] = a;
            }
            __builtin_amdgcn_s_setprio(0);
#pragma unroll
            for (int nb = 0; nb < 2; nb++)
#pragma unroll
                for (int r = 0; r < 4; r++) {
                    const int ti = j0 + nb * 16 + li + 31 - (g * 16 + quad * 4 + r);
                    s[nb][r] = exp2f(fmaf(s[nb][r], SC, tab[ti]));
                }
#pragma unroll
            for (int nb = 0; nb < 2; nb++)
#pragma unroll
                for (int r = 0; r < 4; r++)
                    Ps[quad * 4 + r][nb * 16 + li] = f2b(s[nb][r]);
            const bf16x8 ap = *(const bf16x8*)&Ps[li][quad * 8];
            __builtin_amdgcn_s_setprio(1);
#pragma unroll
            for (int nb = 0; nb < 4; nb++)
                o[g][nb] = __builtin_amdgcn_mfma_f32_16x16x32_bf16(ap, vf[nb],
                                                                   o[g][nb], 0, 0, 0);
            lac[g] = __builtin_amdgcn_mfma_f32_16x16x32_bf16(ap, ones, lac[g], 0, 0, 0);
            __builtin_amdgcn_s_setprio(0);
        }
    }

#pragma unroll
    for (int g = 0; g < 2; g++)
#pragma unroll
        for (int r = 0; r < 4; r++) {
            const float inv = 1.0f / lac[g][r];
            const int qi = q0 + g * 16 + quad * 4 + r;
#pragma unroll
            for (int nb = 0; nb < 4; nb++)
                oz[(size_t)qi * 1024 + h * 64 + nb * 16 + li] = f2b(o[g][nb][r] * inv);
        }
}

// ---------------------------------------------------------------------------
// Launcher. Fast path (ws >= 56 MB + 256; measured ws = 256 MB):
//   F_A|F_B|F_C (24 MB) + WT (8) + F_X (8) + F_Y (6) + WT2 (8) = 54 MB.
// Round-8 schedule (best: 481.9 µs) with the three standalone GEMMs moved
// to gemm_t64 (64x64 tiles, 4 blocks/CU). Fallback: round-7 plan (24 MB).
// ---------------------------------------------------------------------------
extern "C" void kernel_launch(void* const* d_in, const int* in_sizes, int n_in,
                              void* d_out, int out_size, void* d_ws, size_t ws_size,
                              hipStream_t stream) {
    const long M1 = 1024 * 1024;
    const long M2 = 2 * 1024 * 1024;
    const long M4 = 4 * 1024 * 1024;
    if (ws_size < 24u * 1024 * 1024 + 256) return;

    const void* x      = d_in[0];
    const void* ctx    = d_in[1];
    const void* sa_ng  = d_in[2];
    const void* sa_nb  = d_in[3];
    const void* sa_ncg = d_in[4];
    const void* sa_ncb = d_in[5];
    const void* sa_wq  = d_in[6];
    const void* sa_wkv = d_in[7];
    const void* sa_wo  = d_in[8];
    const void* sa_bo  = d_in[9];
    const void* sa_rel = d_in[10];
    const void* ca_ng  = d_in[11];
    const void* ca_nb  = d_in[12];
    const void* ca_ncg = d_in[13];
    const void* ca_ncb = d_in[14];
    const void* ca_wq  = d_in[15];
    const void* ca_wkv = d_in[16];
    const void* ca_wo  = d_in[17];
    const void* ca_bo  = d_in[18];
    const void* ca_rel = d_in[19];

    int* flag = (int*)d_ws;
    bf16* F_A = (bf16*)((char*)d_ws + 256);
    bf16* F_B = F_A + M4;
    bf16* F_C = F_B + M4;
    bf16* WT  = F_C + M4;                // fast path only (SA weights)
    bf16* F_X = WT + M4;                 // fast path only (xn buffer)
    bf16* F_Y = F_X + M4;                // fast path only (ctx-LN + CA K/V)
    bf16* WT2 = F_Y + 3 * M1;            // fast path only (CA weights)
    bf16* qd  = (bf16*)d_out;            // d_out as bf16 scratch (q / ao)

    sniff_kernel<<<1, 256, 0, stream>>>(x, flag);

    if (ws_size >= 56u * 1024 * 1024 + 256) {
        bf16* WTq  = WT;                 // [1024][1024]
        bf16* WTkv = WT + M1;            // [2048][1024]
        bf16* WTo  = WT + 3 * M1;        // [1024][1024]
        bf16* WT2q  = WT2;
        bf16* WT2kv = WT2 + M1;
        bf16* WT2o  = WT2 + 3 * M1;
        bf16* CAK0 = F_Y + M1;           // z0: K[512][1024] + V^T[1024][512]
        bf16* CAK1 = F_Y + 2 * M1;       // z1: same layout

        // ===== prologue: all weight transposes + both input LNs =====
        wconv8_kernel<<<dim3(16, 16, 8), 256, 0, stream>>>(
            sa_wq, sa_wkv, sa_wo, ca_wq, ca_wkv, ca_wo,
            WTq, WTkv, WTo, WT2q, WT2kv, WT2o, flag);
        ln_dual_kernel<<<dim3(2048, 1, 2), 256, 0, stream>>>(
            x, 0, M2, 1, sa_ng, sa_nb, sa_ncg, sa_ncb, F_X, F_B, M2, flag);
        ln_dual_kernel<<<dim3(512, 1, 2), 256, 0, stream>>>(
            ctx, 0, 512 * 1024, 1, ca_ncg, ca_ncb, nullptr, nullptr,
            F_Y, nullptr, 512 * 1024, flag);

        // ===== BIG: SA-q + SA-kv + CA-kv (all independent) =====
        {
            GArgs gq = {};
            gq.A = F_X; gq.Bt = WTq; gq.C = qd;
            gq.N = 1024; gq.nbx = 8; gq.nby = 32;
            GArgs gkv = {};
            gkv.A = F_B; gkv.Bt = WTkv;
            gkv.N = 2048; gkv.mode = 1; gkv.zsplit = 2048; gkv.zrows = 2048;
            gkv.kb0 = F_A; gkv.kb1 = F_C; gkv.nbx = 16; gkv.nby = 32;
            GArgs gca = {};
            gca.A = F_Y; gca.Bt = WT2kv;
            gca.N = 2048; gca.mode = 1; gca.zsplit = 512; gca.zrows = 512;
            gca.kb0 = CAK0; gca.kb1 = CAK1; gca.nbx = 16; gca.nby = 8;
            gemm_fused<<<dim3(40, 32), 256, 0, stream>>>(gq, gkv, gca, flag);
        }

        // ===== self-attention + o-proj (64x64 tile, 4 blocks/CU) =====
        attn_flash<<<dim3(2048), 64, 0, stream>>>(
            qd, F_A, F_C, sa_rel, qd, M2, M2, 2048, 0, flag);
        gemm_t64<<<dim3(16, 64), 256, 0, stream>>>(
            qd, WTo, F_B, 0, sa_bo, x, 1, 1024, flag);

        // ===== cross-attention =====
        ln_dual_kernel<<<dim3(2048, 1, 2), 256, 0, stream>>>(
            F_B, 0, M2, 0, ca_ng, ca_nb, nullptr, nullptr, F_X, nullptr, M2, flag);
        gemm_t64<<<dim3(16, 64), 256, 0, stream>>>(
            F_X, WT2q, qd, 0, nullptr, nullptr, 0, 1024, flag);
        attn_flash<<<dim3(2048), 64, 0, stream>>>(
            qd, CAK0, CAK1, ca_rel, F_C, M2, M2, 512, 1536, flag);
        gemm_t64<<<dim3(16, 64), 256, 0, stream>>>(
            F_C, WT2o, d_out, 1, ca_bo, F_B, 0, 1024, flag);
        return;
    }

    // ================= fallback: round-7 verified plan =================
    ln_dual_kernel<<<dim3(2048, 1, 2), 256, 0, stream>>>(
        x, 0, M2, 1, sa_ng, sa_nb, sa_ncg, sa_ncb, F_A, F_B, M2, flag);
    gemm_mfma<<<dim3(16, 32, 2), 256, 0, stream>>>(
        F_A, M2, sa_wq, qd, 0, M2, 0, nullptr, nullptr, 0, 0, 0,
        1024, 1024, 0, 0, nullptr, nullptr, flag);
    gemm_mfma<<<dim3(32, 32, 2), 256, 0, stream>>>(
        F_B, M2, sa_wkv, nullptr, 0, 0, 0, nullptr, nullptr, 0, 0, 0,
        1024, 2048, 1, 2048, F_A, F_C, flag);
    attn_flash<<<dim3(2048), 64, 0, stream>>>(
        qd, F_A, F_C, sa_rel, qd, M2, M2, 2048, 0, flag);
    gemm_mfma<<<dim3(16, 32, 2), 256, 0, stream>>>(
        qd, M2, sa_wo, F_B, 0, M2, 0, sa_bo, x, 0, M2, 1,
        1024, 1024, 0, 0, nullptr, nullptr, flag);

    ln_dual_kernel<<<dim3(2048, 1, 2), 256, 0, stream>>>(
        F_B, 0, M2, 0, ca_ng, ca_nb, nullptr, nullptr, F_A, nullptr, M2, flag);
    ln_dual_kernel<<<dim3(512, 1, 2), 256, 0, stream>>>(
        ctx, 0, 512 * 1024, 1, ca_ncg, ca_ncb, nullptr, nullptr,
        F_C, nullptr, 512 * 1024, flag);
    gemm_mfma<<<dim3(16, 32, 2), 256, 0, stream>>>(
        F_A, M2, ca_wq, qd, 0, M2, 0, nullptr, nullptr, 0, 0, 0,
        1024, 1024, 0, 0, nullptr, nullptr, flag);
    gemm_mfma<<<dim3(32, 8, 2), 256, 0, stream>>>(
        F_C, 512 * 1024, ca_wkv, nullptr, 0, 0, 0, nullptr, nullptr, 0, 0, 0,
        1024, 2048, 1, 512, F_A, F_A + M1, flag);
    attn_flash<<<dim3(2048), 64, 0, stream>>>(
        qd, F_A, F_A + M1, ca_rel, F_C, M2, M2, 512, 1536, flag);
    gemm_mfma<<<dim3(16, 32, 2), 256, 0, stream>>>(
        F_C, M2, ca_wo, d_out, 0, M2, 1, ca_bo, F_B, 0, M2, 0,
        1024, 1024, 0, 0, nullptr, nullptr, flag);
}